// Round 1
// 489.287 us; speedup vs baseline: 1.0203x; 1.0203x over previous
//
#include <hip/hip_runtime.h>

// ============================================================================
// AdapterAttention on gfx950.
// R3: GEMMs rewritten from the m97 structure (128^2, __syncthreads = vmcnt(0)
//     drain per K-step, 37% MfmaUtil ceiling) to a T3+T4 deep pipeline:
//     256x128 tile, 8 waves, BK=32, ring of 4 LDS K-tile buffers (96 KiB),
//     staging 3 tiles ahead, counted s_waitcnt vmcnt(6) (never 0 in-loop),
//     raw s_barrier, setprio(1) around the 16-MFMA cluster (T5).
//     Grids: qkv 16x16x3=768 blocks (3 exact CU-waves), out-proj 16x16=256
//     blocks (1 exact CU-wave). flash: +setprio around MFMA clusters.
// ============================================================================

typedef __attribute__((ext_vector_type(8))) short bf16x8;
typedef __attribute__((ext_vector_type(4))) float f32x4;

#define AS1(p) ((__attribute__((address_space(1))) void*)(p))
#define AS3(p) ((__attribute__((address_space(3))) void*)(p))

__device__ __forceinline__ unsigned short f2bf(float f) {
  unsigned int u = __float_as_uint(f);
  u += 0x7fffu + ((u >> 16) & 1u);   // RNE; inputs are finite
  return (unsigned short)(u >> 16);
}
__device__ __forceinline__ float bf2f(unsigned short u) {
  return __uint_as_float(((unsigned int)u) << 16);
}

constexpr int B_ = 2, S_ = 2048, DM = 2048, H_ = 16, HD = 128;
constexpr int M_ = B_ * S_;  // 4096 rows

// ---------------- fp32 -> bf16 cast (vec4) ----------------
__global__ __launch_bounds__(256) void castbf(const float* __restrict__ X,
                                              unsigned short* __restrict__ Y, int n4) {
  int i = blockIdx.x * 256 + threadIdx.x;
  if (i >= n4) return;
  float4 v = ((const float4*)X)[i];
  ushort4 u;
  u.x = f2bf(v.x); u.y = f2bf(v.y); u.z = f2bf(v.z); u.w = f2bf(v.w);
  ((ushort4*)Y)[i] = u;
}

// ---------------- deep-pipelined 256x128 GEMM core (C = A * W^T) ------------
// 512 threads = 8 waves as 4(M) x 2(N); per-wave 64x64 output (4x4 frags).
// LDS ring: 4 buffers x (A 256x32 + B 128x32) bf16 = 96 KiB.
// Per tile per thread: 3 global_load_lds (A:2, B:1). Steady vmcnt(6) = 2 tiles.
template <int BF16OUT>
__device__ __forceinline__ void gemm_core(const unsigned short* __restrict__ A,
                                          const unsigned short* __restrict__ Bw,
                                          void* __restrict__ Cv,
                                          unsigned short* lA, unsigned short* lB) {
  const int tid = threadIdx.x, wave = tid >> 6, lane = tid & 63;
  const int quad = lane >> 4, l16 = lane & 15;
  const int m0 = blockIdx.x * 256, n0 = blockIdx.y * 128;
  const int wm = (wave >> 1) * 64, wn = (wave & 1) * 64;
  constexpr int NT = DM / 32;  // 64 K-tiles

  f32x4 acc[4][4];
#pragma unroll
  for (int i = 0; i < 4; i++)
#pragma unroll
    for (int j = 0; j < 4; j++) acc[i][j] = (f32x4){0.f, 0.f, 0.f, 0.f};

  // staging addresses (pre-swizzled global source, linear LDS dest)
  const int c0 = wave * 64 + lane;                       // chunk id [0,512)
  const int rA0 = c0 >> 2, dA0 = (c0 & 3) ^ ((rA0 >> 1) & 3);
  const int c1 = 512 + c0;                               // chunk id [512,1024)
  const int rA1 = c1 >> 2, dA1 = (c1 & 3) ^ ((rA1 >> 1) & 3);
  const unsigned short* gA0 = A + (size_t)(m0 + rA0) * DM + dA0 * 8;
  const unsigned short* gA1 = A + (size_t)(m0 + rA1) * DM + dA1 * 8;
  const unsigned short* gB  = Bw + (size_t)(n0 + rA0) * DM + dA0 * 8;
  const int wdst = wave * 512;  // shorts; +lane*16B implicit in global_load_lds

#define STAGE(T)                                                                         \
  {                                                                                      \
    const int b_ = (T) & 3; const int k_ = (T) << 5;                                     \
    __builtin_amdgcn_global_load_lds(AS1(gA0 + k_), AS3(lA + b_ * 8192 + wdst), 16, 0, 0);\
    __builtin_amdgcn_global_load_lds(AS1(gA1 + k_), AS3(lA + b_ * 8192 + 4096 + wdst), 16, 0, 0);\
    __builtin_amdgcn_global_load_lds(AS1(gB + k_),  AS3(lB + b_ * 4096 + wdst), 16, 0, 0);\
  }

  STAGE(0) STAGE(1) STAGE(2)

  const int xoff = (quad ^ ((l16 >> 1) & 3)) * 8;  // read-side chunk swizzle

  for (int t = 0; t < NT; ++t) {
    // Boundary guard: tile t fully staged collectively after {vmcnt(N); barrier}.
    // Outstanding allowed: tiles t+1,t+2 (3 loads each). Never drains in-loop.
    if (t < NT - 2)       asm volatile("s_waitcnt vmcnt(6)\n\ts_barrier" ::: "memory");
    else if (t == NT - 2) asm volatile("s_waitcnt vmcnt(3)\n\ts_barrier" ::: "memory");
    else                  asm volatile("s_waitcnt vmcnt(0)\n\ts_barrier" ::: "memory");

    const unsigned short* ab = lA + (t & 3) * 8192;
    const unsigned short* bb = lB + (t & 3) * 4096;
    bf16x8 af[4], bf[4];
#pragma unroll
    for (int i = 0; i < 4; i++)
      af[i] = *(const bf16x8*)(ab + (wm + i * 16 + l16) * 32 + xoff);
#pragma unroll
    for (int j = 0; j < 4; j++)
      bf[j] = *(const bf16x8*)(bb + (wn + j * 16 + l16) * 32 + xoff);

    if (t + 3 < NT) STAGE(t + 3)   // into buf[(t+3)&3] = buf[(t-1)&3], free now

    __builtin_amdgcn_s_barrier();  // phase alignment: all waves enter MFMA together
    __builtin_amdgcn_s_setprio(1);
#pragma unroll
    for (int i = 0; i < 4; i++)
#pragma unroll
      for (int j = 0; j < 4; j++)
        acc[i][j] = __builtin_amdgcn_mfma_f32_16x16x32_bf16(af[i], bf[j], acc[i][j], 0, 0, 0);
    __builtin_amdgcn_s_setprio(0);
  }
#undef STAGE

#pragma unroll
  for (int i = 0; i < 4; i++)
#pragma unroll
    for (int j = 0; j < 4; j++) {
      const size_t row = (size_t)(m0 + wm + i * 16 + quad * 4);
      const int col = n0 + wn + j * 16 + l16;
      if (BF16OUT) {
        unsigned short* cp = (unsigned short*)Cv + row * DM + col;
#pragma unroll
        for (int r = 0; r < 4; r++) cp[(size_t)r * DM] = f2bf(acc[i][j][r]);
      } else {
        float* cp = (float*)Cv + row * DM + col;
#pragma unroll
        for (int r = 0; r < 4; r++) cp[(size_t)r * DM] = acc[i][j][r];
      }
    }
}

// ---------------- batched QKV GEMM: P[z] = A[z] * W[z]^T, bf16 out ----------
__global__ __launch_bounds__(512, 2) void gemm_qkv(const unsigned short* __restrict__ xb,
                                                   const unsigned short* __restrict__ cb,
                                                   const unsigned short* __restrict__ Wq,
                                                   const unsigned short* __restrict__ Wk,
                                                   const unsigned short* __restrict__ Wv,
                                                   unsigned short* __restrict__ Pq,
                                                   unsigned short* __restrict__ Pk,
                                                   unsigned short* __restrict__ Pv) {
  __shared__ __align__(16) unsigned short lA[4 * 8192];
  __shared__ __align__(16) unsigned short lB[4 * 4096];
  const int z = blockIdx.z;
  const unsigned short* A  = (z == 0) ? xb : cb;
  const unsigned short* Bw = (z == 0) ? Wq : (z == 1) ? Wk : Wv;
  unsigned short* C        = (z == 0) ? Pq : (z == 1) ? Pk : Pv;
  gemm_core<1>(A, Bw, C, lA, lB);
}

// ---------------- bf16 GEMM: C = A * W^T (fp32 out), for out-proj -----------
__global__ __launch_bounds__(512, 2) void gemm_bt(const unsigned short* __restrict__ A,
                                                  const unsigned short* __restrict__ Bw,
                                                  float* __restrict__ C) {
  __shared__ __align__(16) unsigned short lA[4 * 8192];
  __shared__ __align__(16) unsigned short lB[4 * 4096];
  gemm_core<0>(A, Bw, C, lA, lB);
}

// ---------------- fused RMSNorm + RoPE, bf16 (B,S,H,hd) -> (B,H,S,hd) bf16 --
__global__ __launch_bounds__(256) void normrope(const unsigned short* __restrict__ X,
                                                const float* __restrict__ Cs,
                                                const float* __restrict__ Sn,
                                                const float* __restrict__ W,
                                                unsigned short* __restrict__ Out,
                                                float scale) {
  int gw = (blockIdx.x * 256 + threadIdx.x) >> 6;  // (b*S+s)*H + h
  int lane = threadIdx.x & 63;
  int h = gw & 15, bs = gw >> 4;          // bs = b*S + s
  int s = bs & (S_ - 1), b = bs >> 11;
  const unsigned short* xr = X + (size_t)gw * HD;
  float x0 = bf2f(xr[lane]), x1 = bf2f(xr[lane + 64]);
  float ss = x0 * x0 + x1 * x1;
#pragma unroll
  for (int off = 32; off > 0; off >>= 1) ss += __shfl_xor(ss, off);
  float rr = rsqrtf(ss * (1.0f / 128.0f) + 1e-6f);
  float n0 = x0 * rr * W[lane], n1 = x1 * rr * W[lane + 64];
  const float* cp = Cs + (size_t)bs * HD;
  const float* sp = Sn + (size_t)bs * HD;
  float o0 = (n0 * cp[lane] - n1 * sp[lane]) * scale;
  float o1 = (n1 * cp[lane + 64] + n0 * sp[lane + 64]) * scale;
  unsigned short* orow = Out + (((size_t)(b * H_ + h)) * S_ + s) * HD;
  orow[lane] = f2bf(o0);
  orow[lane + 64] = f2bf(o1);
}

// ---------------- V: bf16 (B,S,H,hd) -> (B*H, hd, Sk) bf16 (transposed) -----
__global__ __launch_bounds__(256) void vtrans(const unsigned short* __restrict__ Vf,
                                              unsigned short* __restrict__ Vt) {
  __shared__ unsigned short tile[128 * 72];  // [d][s], stride 72
  const int tid = threadIdx.x;
  const int sc = blockIdx.x & 31;
  const int bh = blockIdx.x >> 5;
  const int b = bh >> 4, h = bh & 15;
  const int s0 = sc * 64;
#pragma unroll
  for (int it = 0; it < 4; ++it) {
    int ci = it * 256 + tid;                  // 1024 chunks: 64 s x 16 dc
    int s = ci >> 4, dc = ci & 15;
    bf16x8 v = *(const bf16x8*)(Vf + ((size_t)(b * S_ + s0 + s)) * DM + h * HD + dc * 8);
    unsigned short* tp = tile + (dc * 8) * 72 + s;
#pragma unroll
    for (int e = 0; e < 8; e++) tp[e * 72] = (unsigned short)v[e];
  }
  __syncthreads();
#pragma unroll
  for (int it = 0; it < 4; ++it) {
    int cj = it * 256 + tid;                  // 1024 16B chunks: 128 d x 8 sc
    int d = cj >> 3, scx = cj & 7;
    bf16x8 vv = *(const bf16x8*)(tile + d * 72 + scx * 8);
    *(bf16x8*)(Vt + ((size_t)bh * HD + d) * S_ + s0 + scx * 8) = vv;
  }
}

// ---------------- flash attention v3 ----------------
// 128 threads (2 waves), 64 q-rows/block (32/wave), 64-key chunks.
// Q (BH,Sq,128) bf16 scale-baked; K (BH,Sk,128); V (BH,128,Sk); Y (B,Sq,2048) bf16
__global__ __launch_bounds__(128) void flash(const unsigned short* __restrict__ Q,
                                             const unsigned short* __restrict__ Kt,
                                             const unsigned short* __restrict__ Vt,
                                             unsigned short* __restrict__ Y) {
  __shared__ unsigned short lK[64 * HD];      // [key][dim], chunk-swizzled
  __shared__ unsigned short lV[HD * 64];      // [dim][key], chunk-swizzled
  __shared__ unsigned short lP[2 * 1024];     // per-wave P scratch (reused per half)
  const int tid = threadIdx.x, wave = tid >> 6, lane = tid & 63;
  const int quad = lane >> 4, l16 = lane & 15;
  const int qb = blockIdx.x & 31;   // Sq/64
  const int bh = blockIdx.x >> 5;
  const int b = bh >> 4, h = bh & 15;
  const int q0 = qb * 64 + wave * 32;

  bf16x8 aq[2][4];
#pragma unroll
  for (int u = 0; u < 2; u++) {
    const unsigned short* qrow = Q + ((size_t)bh * S_ + q0 + u * 16 + l16) * HD;
#pragma unroll
    for (int t = 0; t < 4; t++) aq[u][t] = *(const bf16x8*)(qrow + t * 32 + quad * 8);
  }
  f32x4 o[2][8];
#pragma unroll
  for (int u = 0; u < 2; u++)
#pragma unroll
    for (int t = 0; t < 8; t++) o[u][t] = (f32x4){0.f, 0.f, 0.f, 0.f};
  float lsum[2][4] = {{0.f, 0.f, 0.f, 0.f}, {0.f, 0.f, 0.f, 0.f}};

  const unsigned short* kbase = Kt + (size_t)bh * S_ * HD;
  const unsigned short* vbase = Vt + (size_t)bh * HD * S_;
  unsigned short* lPw = lP + wave * 1024;
  const int mrow = quad * 4;
  const int xsl = (l16 >> 1) & 3;    // P-read swizzle (4 chunks per 32-key row)
  const int xsl7 = (l16 >> 1) & 7;   // V-read swizzle (8 chunks per 64-key row)

  for (int k0 = 0; k0 < S_; k0 += 64) {
    __syncthreads();
#pragma unroll
    for (int call = 0; call < 8; ++call) {
      int c = call * 128 + wave * 64 + lane;  // 1024 chunks of 16B each
      int key = c >> 4, sk = c & 15;          // K: 64 keys x 16 dim-chunks
      int dck = sk ^ (key & 15);
      __builtin_amdgcn_global_load_lds(AS1(kbase + (size_t)(k0 + key) * HD + dck * 8),
                                       AS3(lK + (call * 128 + wave * 64) * 8), 16, 0, 0);
      int dv = c >> 3, sv = c & 7;            // V: 128 dims x 8 key-chunks
      int kc = sv ^ ((dv >> 1) & 7);
      __builtin_amdgcn_global_load_lds(AS1(vbase + (size_t)dv * S_ + k0 + kc * 8),
                                       AS3(lV + (call * 128 + wave * 64) * 8), 16, 0, 0);
    }
    __syncthreads();

#pragma unroll
    for (int h2 = 0; h2 < 2; ++h2) {          // two 32-key halves
      // S = Q*K^T  (two 16-key tiles x two 16-row q subtiles; K frags shared)
      f32x4 s0[2] = {(f32x4){0.f, 0.f, 0.f, 0.f}, (f32x4){0.f, 0.f, 0.f, 0.f}};
      f32x4 s1[2] = {(f32x4){0.f, 0.f, 0.f, 0.f}, (f32x4){0.f, 0.f, 0.f, 0.f}};
      {
        const unsigned short* krow0 = lK + (h2 * 32 + l16) * HD;
        const unsigned short* krow1 = krow0 + 16 * HD;
        __builtin_amdgcn_s_setprio(1);
#pragma unroll
        for (int t = 0; t < 4; t++) {
          int dcq = t * 4 + quad;
          bf16x8 kf0 = *(const bf16x8*)(krow0 + (dcq ^ l16) * 8);
          bf16x8 kf1 = *(const bf16x8*)(krow1 + (dcq ^ l16) * 8);
#pragma unroll
          for (int u = 0; u < 2; u++) {
            s0[u] = __builtin_amdgcn_mfma_f32_16x16x32_bf16(aq[u][t], kf0, s0[u], 0, 0, 0);
            s1[u] = __builtin_amdgcn_mfma_f32_16x16x32_bf16(aq[u][t], kf1, s1[u], 0, 0, 0);
          }
        }
        __builtin_amdgcn_s_setprio(0);
      }
      // softmax numerator (no max subtraction: |s| <= 22.6)
#pragma unroll
      for (int u = 0; u < 2; u++) {
        unsigned short* lPu = lPw + u * 512;
#pragma unroll
        for (int r = 0; r < 4; r++) {
          int m = mrow + r;
          int sx = (m >> 1) & 3;
          float p0 = __expf(s0[u][r]);
          float p1 = __expf(s1[u][r]);
          lsum[u][r] += p0 + p1;
          int kc0 = l16 >> 3;
          lPu[m * 32 + ((kc0 ^ sx)) * 8 + (l16 & 7)] = f2bf(p0);
          lPu[m * 32 + (((kc0 + 2) ^ sx)) * 8 + (l16 & 7)] = f2bf(p1);
        }
      }
      // P: C-layout -> A-layout via LDS (in-wave ordered, no barrier needed)
      bf16x8 pf[2];
#pragma unroll
      for (int u = 0; u < 2; u++)
        pf[u] = *(const bf16x8*)(lPw + u * 512 + l16 * 32 + (quad ^ xsl) * 8);
      // O += P * V  (V frags shared across u)
      __builtin_amdgcn_s_setprio(1);
#pragma unroll
      for (int t = 0; t < 8; t++) {
        bf16x8 vf = *(const bf16x8*)(lV + (t * 16 + l16) * 64 + ((h2 * 4 + quad) ^ xsl7) * 8);
#pragma unroll
        for (int u = 0; u < 2; u++)
          o[u][t] = __builtin_amdgcn_mfma_f32_16x16x32_bf16(pf[u], vf, o[u][t], 0, 0, 0);
      }
      __builtin_amdgcn_s_setprio(0);
    }
  }

  // reduce row-sums across the 16 lanes of each quad
#pragma unroll
  for (int off = 1; off < 16; off <<= 1) {
#pragma unroll
    for (int u = 0; u < 2; u++)
#pragma unroll
      for (int r = 0; r < 4; r++) lsum[u][r] += __shfl_xor(lsum[u][r], off);
  }
  float inv[2][4];
#pragma unroll
  for (int u = 0; u < 2; u++)
#pragma unroll
    for (int r = 0; r < 4; r++) inv[u][r] = 1.0f / lsum[u][r];
#pragma unroll
  for (int u = 0; u < 2; u++)
#pragma unroll
    for (int t = 0; t < 8; t++)
#pragma unroll
      for (int r = 0; r < 4; r++) {
        size_t idx = ((size_t)b * S_ + q0 + u * 16 + mrow + r) * DM + h * HD + t * 16 + l16;
        Y[idx] = f2bf(o[u][t][r] * inv[u][r]);
      }
}

// ============================================================================
extern "C" void kernel_launch(void* const* d_in, const int* in_sizes, int n_in,
                              void* d_out, int out_size, void* d_ws, size_t ws_size,
                              hipStream_t stream) {
  const float* x    = (const float*)d_in[0];
  const float* ctx  = (const float*)d_in[1];
  const float* cosq = (const float*)d_in[2];
  const float* sinq = (const float*)d_in[3];
  const float* cosk = (const float*)d_in[4];
  const float* sink = (const float*)d_in[5];
  const float* Wq   = (const float*)d_in[6];
  const float* Wk   = (const float*)d_in[7];
  const float* Wv   = (const float*)d_in[8];
  const float* Wo   = (const float*)d_in[9];
  const float* qw   = (const float*)d_in[10];
  const float* kw   = (const float*)d_in[11];

  // ---- workspace layout with lifetime overlap (~118 MB) ----
  char* ws = (char*)d_ws;
  const size_t ACT2 = (size_t)M_ * DM * 2;   // 16.8 MB bf16 activation
  const size_t W2   = (size_t)DM * DM * 2;   // 8.4 MB bf16 weight
  unsigned short* xb  = (unsigned short*)(ws);                    // -> qn
  unsigned short* cb  = (unsigned short*)(ws + ACT2);             // -> vt
  unsigned short* Wqb = (unsigned short*)(ws + 2 * ACT2);         // \ kn
  unsigned short* Wkb = (unsigned short*)(ws + 2 * ACT2 + W2);    // /
  unsigned short* Wvb = (unsigned short*)(ws + 2 * ACT2 + 2 * W2);
  unsigned short* Wob = (unsigned short*)(ws + 2 * ACT2 + 3 * W2);
  unsigned short* Pq  = (unsigned short*)(ws + 2 * ACT2 + 4 * W2);  // -> yb
  unsigned short* Pk  = (unsigned short*)(ws + 3 * ACT2 + 4 * W2);
  unsigned short* Pv  = (unsigned short*)(ws + 4 * ACT2 + 4 * W2);
  unsigned short* qn = xb;          // after gemm_qkv consumed xb
  unsigned short* kn = Wqb;         // spans Wqb+Wkb, dead after gemm_qkv
  unsigned short* vt = cb;          // after gemm_qkv consumed cb
  unsigned short* yb = Pq;          // after normrope consumed Pq

  const float scale = 0.0883883476483184f;  // 1/sqrt(128)

  castbf<<<M_ * DM / 1024, 256, 0, stream>>>(x, xb, M_ * DM / 4);
  castbf<<<M_ * DM / 1024, 256, 0, stream>>>(ctx, cb, M_ * DM / 4);
  castbf<<<DM * DM / 1024, 256, 0, stream>>>(Wq, Wqb, DM * DM / 4);
  castbf<<<DM * DM / 1024, 256, 0, stream>>>(Wk, Wkb, DM * DM / 4);
  castbf<<<DM * DM / 1024, 256, 0, stream>>>(Wv, Wvb, DM * DM / 4);
  castbf<<<DM * DM / 1024, 256, 0, stream>>>(Wo, Wob, DM * DM / 4);

  dim3 gq(M_ / 256, DM / 128, 3);   // 16 x 16 x 3 = 768 blocks = 3 full CU-waves
  gemm_qkv<<<gq, 512, 0, stream>>>(xb, cb, Wqb, Wkb, Wvb, Pq, Pk, Pv);

  normrope<<<M_ * H_ / 4, 256, 0, stream>>>(Pq, cosq, sinq, qw, qn, scale);
  normrope<<<M_ * H_ / 4, 256, 0, stream>>>(Pk, cosk, sink, kw, kn, 1.0f);
  vtrans<<<B_ * H_ * (S_ / 64), 256, 0, stream>>>(Pv, vt);

  flash<<<B_ * H_ * (S_ / 64), 128, 0, stream>>>(qn, kn, vt, yb);

  dim3 gg(M_ / 256, DM / 128);      // 16 x 16 = 256 blocks = 1 full CU-wave
  gemm_bt<<<gg, 512, 0, stream>>>(yb, Wob, (float*)d_out);

  (void)in_sizes; (void)n_in; (void)out_size; (void)ws_size;
}

// Round 2
// 483.309 us; speedup vs baseline: 1.0329x; 1.0124x over previous
//
#include <hip/hip_runtime.h>

// ============================================================================
// AdapterAttention on gfx950.
// R4: GEMMs use the verified 8-phase-style schedule (m201 template) adapted to
//     BM=256 x BN=128 x BK=64 with a 3-deep LDS ring (144 KiB) so prefetch is
//     hazard-free by construction. Per K-tile: 2 phases x {ds_read (12/4 x
//     b128, XOR-swizzled) | issue 3 global_load_lds | barrier | setprio(1) |
//     16 MFMA | setprio(0) | [vmcnt(6) gate once/K-tile] | barrier}. Counted
//     vmcnt never drains to 0 until the epilogue. Grids: qkv 16x16x3=768
//     blocks (3 exact CU-rounds), out-proj 16x16=256 (1 exact round).
//     R3 lesson (m196 confirmed): coarse 1-phase counted-vmcnt REGRESSES;
//     the fine per-phase interleave is the lever.
// ============================================================================

typedef __attribute__((ext_vector_type(8))) short bf16x8;
typedef __attribute__((ext_vector_type(4))) float f32x4;

#define AS1(p) ((__attribute__((address_space(1))) void*)(p))
#define AS3(p) ((__attribute__((address_space(3))) void*)(p))
#define STG(g, l) __builtin_amdgcn_global_load_lds(AS1(g), AS3(l), 16, 0, 0)

__device__ __forceinline__ unsigned short f2bf(float f) {
  unsigned int u = __float_as_uint(f);
  u += 0x7fffu + ((u >> 16) & 1u);   // RNE; inputs are finite
  return (unsigned short)(u >> 16);
}
__device__ __forceinline__ float bf2f(unsigned short u) {
  return __uint_as_float(((unsigned int)u) << 16);
}

constexpr int B_ = 2, S_ = 2048, DM = 2048, H_ = 16, HD = 128;
constexpr int M_ = B_ * S_;  // 4096 rows

// ---------------- fp32 -> bf16 cast (vec4) ----------------
__global__ __launch_bounds__(256) void castbf(const float* __restrict__ X,
                                              unsigned short* __restrict__ Y, int n4) {
  int i = blockIdx.x * 256 + threadIdx.x;
  if (i >= n4) return;
  float4 v = ((const float4*)X)[i];
  ushort4 u;
  u.x = f2bf(v.x); u.y = f2bf(v.y); u.z = f2bf(v.z); u.w = f2bf(v.w);
  ((ushort4*)Y)[i] = u;
}

// ---------------- 8-phase-style 256x128 GEMM core (C = A * W^T) -------------
// 512 threads = 8 waves as 4(M) x 2(N); per-wave 64x64 output (4x4 frags).
// LDS: ring of 3 K-tile slots, slot = A[256][64] + B[128][64] bf16 = 48 KB.
// Per K-tile per thread: 6 global_load_lds (A:4, B:2), issued 3+3 across the
// two phases, targeting slot (t+2)%3 (never the slot being read).
// Gate: vmcnt(6) at end of each K-tile -> tile t+1 landed, tile t+2 in flight.
template <int BF16OUT>
__device__ __forceinline__ void gemm8_core(const unsigned short* __restrict__ A,
                                           const unsigned short* __restrict__ Bw,
                                           void* __restrict__ Cv,
                                           unsigned short* lds) {
  const int tid = threadIdx.x, wave = tid >> 6, lane = tid & 63;
  const int quad = lane >> 4, l16 = lane & 15;
  const int m0 = blockIdx.x * 256, n0 = blockIdx.y * 128;
  const int wm = (wave >> 1) * 64, wn = (wave & 1) * 64;
  constexpr int NT = DM / 64;    // 32 K-tiles
  constexpr int SLOT = 24576;    // shorts per ring slot (48 KB)

  f32x4 acc[4][4];
#pragma unroll
  for (int i = 0; i < 4; i++)
#pragma unroll
    for (int j = 0; j < 4; j++) acc[i][j] = (f32x4){0.f, 0.f, 0.f, 0.f};

  // -- staging addresses: pre-swizzled global source, linear LDS dest --
  // chunk for this thread: row = tid>>3 (within a 64-row call-group),
  // physical k-chunk ch holds logical chunk (tid&7)^(row&7).
  const int ch = ((tid & 7) ^ ((tid >> 3) & 7)) * 8;
  const unsigned short* gA0 = A + (size_t)(m0 + (tid >> 3)) * DM + ch;
  const unsigned short* gB0 = Bw + (size_t)(n0 + (tid >> 3)) * DM + ch;
  const int wst = wave * 512;  // wave's 64-chunk region within a call (shorts)

  // A call c covers rows [c*64, c*64+64) -> global +c*64*DM = c*131072 shorts,
  // LDS dest +c*4096 shorts. B likewise (2 calls).
#define STG_H0(T, S)                                                          \
  { const unsigned short* g_ = gA0 + (size_t)(T) * 64;                        \
    STG(g_,          lds + (S) * SLOT + wst);                                 \
    STG(g_ + 131072, lds + (S) * SLOT + 4096 + wst);                          \
    STG(gB0 + (size_t)(T) * 64, lds + (S) * SLOT + 16384 + wst); }
#define STG_H1(T, S)                                                          \
  { const unsigned short* g_ = gA0 + (size_t)(T) * 64 + 262144;               \
    STG(g_,          lds + (S) * SLOT + 8192 + wst);                          \
    STG(g_ + 131072, lds + (S) * SLOT + 12288 + wst);                         \
    STG(gB0 + (size_t)(T) * 64 + 131072,                                      \
        lds + (S) * SLOT + 16384 + 4096 + wst); }

  // -- read-side offsets (shorts). Row r, logical chunk C -> physical
  //    chunk C^(r&7). For frag rows r = base16 + l16: r&7 == l16&7.
  const int sx = (quad ^ (l16 & 7)) * 8;       // kh=0 chunk offset
  const int aoff = (wm + l16) * 64;            // A row base
  const int boff = 16384 + (wn + l16) * 64;    // B row base

  // -- prologue: stage tiles 0,1; wait tile 0 (6 newest stay in flight) --
  STG_H0(0, 0) STG_H1(0, 0)
  STG_H0(1, 1) STG_H1(1, 1)
  asm volatile("s_waitcnt vmcnt(6)" ::: "memory");
  __builtin_amdgcn_s_barrier();

  int slot = 0;
  for (int t = 0; t < NT; ++t) {
    const unsigned short* ls = lds + slot * SLOT;
    int s2 = slot + 2; if (s2 >= 3) s2 -= 3;   // slot of tile t+2

    // ---- phase 0: A frags 0,1 + all B frags; stage half 0 of tile t+2 ----
    bf16x8 a0[2][2], bf[4][2];
#pragma unroll
    for (int i = 0; i < 2; i++) {
      a0[i][0] = *(const bf16x8*)(ls + aoff + i * 1024 + sx);
      a0[i][1] = *(const bf16x8*)(ls + aoff + i * 1024 + (sx ^ 32));
    }
#pragma unroll
    for (int j = 0; j < 4; j++) {
      bf[j][0] = *(const bf16x8*)(ls + boff + j * 1024 + sx);
      bf[j][1] = *(const bf16x8*)(ls + boff + j * 1024 + (sx ^ 32));
    }
    if (t + 2 < NT) STG_H0(t + 2, s2)
    __builtin_amdgcn_s_barrier();
    __builtin_amdgcn_s_setprio(1);
#pragma unroll
    for (int i = 0; i < 2; i++)
#pragma unroll
      for (int j = 0; j < 4; j++) {
        acc[i][j] = __builtin_amdgcn_mfma_f32_16x16x32_bf16(a0[i][0], bf[j][0], acc[i][j], 0, 0, 0);
        acc[i][j] = __builtin_amdgcn_mfma_f32_16x16x32_bf16(a0[i][1], bf[j][1], acc[i][j], 0, 0, 0);
      }
    __builtin_amdgcn_s_setprio(0);
    __builtin_amdgcn_s_barrier();

    // ---- phase 1: A frags 2,3 (B reused); stage half 1 of tile t+2 ----
    bf16x8 a1[2][2];
#pragma unroll
    for (int i = 0; i < 2; i++) {
      a1[i][0] = *(const bf16x8*)(ls + aoff + (i + 2) * 1024 + sx);
      a1[i][1] = *(const bf16x8*)(ls + aoff + (i + 2) * 1024 + (sx ^ 32));
    }
    if (t + 2 < NT) STG_H1(t + 2, s2)
    __builtin_amdgcn_s_barrier();
    __builtin_amdgcn_s_setprio(1);
#pragma unroll
    for (int i = 0; i < 2; i++)
#pragma unroll
      for (int j = 0; j < 4; j++) {
        acc[i + 2][j] = __builtin_amdgcn_mfma_f32_16x16x32_bf16(a1[i][0], bf[j][0], acc[i + 2][j], 0, 0, 0);
        acc[i + 2][j] = __builtin_amdgcn_mfma_f32_16x16x32_bf16(a1[i][1], bf[j][1], acc[i + 2][j], 0, 0, 0);
      }
    __builtin_amdgcn_s_setprio(0);
    // ---- gate: tile t+1 must be landed; tile t+2's 6 loads stay in flight --
    if (t < NT - 2)       asm volatile("s_waitcnt vmcnt(6)" ::: "memory");
    else if (t == NT - 2) asm volatile("s_waitcnt vmcnt(0)" ::: "memory");
    __builtin_amdgcn_s_barrier();

    slot++; if (slot == 3) slot = 0;
  }
#undef STG_H0
#undef STG_H1

  // ---- epilogue: C write ----
#pragma unroll
  for (int i = 0; i < 4; i++)
#pragma unroll
    for (int j = 0; j < 4; j++) {
      const size_t row = (size_t)(m0 + wm + i * 16 + quad * 4);
      const int col = n0 + wn + j * 16 + l16;
      if (BF16OUT) {
        unsigned short* cp = (unsigned short*)Cv + row * DM + col;
#pragma unroll
        for (int r = 0; r < 4; r++) cp[(size_t)r * DM] = f2bf(acc[i][j][r]);
      } else {
        float* cp = (float*)Cv + row * DM + col;
#pragma unroll
        for (int r = 0; r < 4; r++) cp[(size_t)r * DM] = acc[i][j][r];
      }
    }
}

// ---------------- batched QKV GEMM: P[z] = A[z] * W[z]^T, bf16 out ----------
__global__ __launch_bounds__(512, 2) void gemm_qkv(const unsigned short* __restrict__ xb,
                                                   const unsigned short* __restrict__ cb,
                                                   const unsigned short* __restrict__ Wq,
                                                   const unsigned short* __restrict__ Wk,
                                                   const unsigned short* __restrict__ Wv,
                                                   unsigned short* __restrict__ Pq,
                                                   unsigned short* __restrict__ Pk,
                                                   unsigned short* __restrict__ Pv) {
  __shared__ __align__(16) unsigned short lds[3 * 24576];  // 144 KiB
  const int z = blockIdx.z;
  const unsigned short* A  = (z == 0) ? xb : cb;
  const unsigned short* Bw = (z == 0) ? Wq : (z == 1) ? Wk : Wv;
  unsigned short* C        = (z == 0) ? Pq : (z == 1) ? Pk : Pv;
  gemm8_core<1>(A, Bw, C, lds);
}

// ---------------- bf16 GEMM: C = A * W^T (fp32 out), for out-proj -----------
__global__ __launch_bounds__(512, 2) void gemm_bt(const unsigned short* __restrict__ A,
                                                  const unsigned short* __restrict__ Bw,
                                                  float* __restrict__ C) {
  __shared__ __align__(16) unsigned short lds[3 * 24576];  // 144 KiB
  gemm8_core<0>(A, Bw, C, lds);
}

// ---------------- fused RMSNorm + RoPE, bf16 (B,S,H,hd) -> (B,H,S,hd) bf16 --
__global__ __launch_bounds__(256) void normrope(const unsigned short* __restrict__ X,
                                                const float* __restrict__ Cs,
                                                const float* __restrict__ Sn,
                                                const float* __restrict__ W,
                                                unsigned short* __restrict__ Out,
                                                float scale) {
  int gw = (blockIdx.x * 256 + threadIdx.x) >> 6;  // (b*S+s)*H + h
  int lane = threadIdx.x & 63;
  int h = gw & 15, bs = gw >> 4;          // bs = b*S + s
  int s = bs & (S_ - 1), b = bs >> 11;
  const unsigned short* xr = X + (size_t)gw * HD;
  float x0 = bf2f(xr[lane]), x1 = bf2f(xr[lane + 64]);
  float ss = x0 * x0 + x1 * x1;
#pragma unroll
  for (int off = 32; off > 0; off >>= 1) ss += __shfl_xor(ss, off);
  float rr = rsqrtf(ss * (1.0f / 128.0f) + 1e-6f);
  float n0 = x0 * rr * W[lane], n1 = x1 * rr * W[lane + 64];
  const float* cp = Cs + (size_t)bs * HD;
  const float* sp = Sn + (size_t)bs * HD;
  float o0 = (n0 * cp[lane] - n1 * sp[lane]) * scale;
  float o1 = (n1 * cp[lane + 64] + n0 * sp[lane + 64]) * scale;
  unsigned short* orow = Out + (((size_t)(b * H_ + h)) * S_ + s) * HD;
  orow[lane] = f2bf(o0);
  orow[lane + 64] = f2bf(o1);
}

// ---------------- V: bf16 (B,S,H,hd) -> (B*H, hd, Sk) bf16 (transposed) -----
__global__ __launch_bounds__(256) void vtrans(const unsigned short* __restrict__ Vf,
                                              unsigned short* __restrict__ Vt) {
  __shared__ unsigned short tile[128 * 72];  // [d][s], stride 72
  const int tid = threadIdx.x;
  const int sc = blockIdx.x & 31;
  const int bh = blockIdx.x >> 5;
  const int b = bh >> 4, h = bh & 15;
  const int s0 = sc * 64;
#pragma unroll
  for (int it = 0; it < 4; ++it) {
    int ci = it * 256 + tid;                  // 1024 chunks: 64 s x 16 dc
    int s = ci >> 4, dc = ci & 15;
    bf16x8 v = *(const bf16x8*)(Vf + ((size_t)(b * S_ + s0 + s)) * DM + h * HD + dc * 8);
    unsigned short* tp = tile + (dc * 8) * 72 + s;
#pragma unroll
    for (int e = 0; e < 8; e++) tp[e * 72] = (unsigned short)v[e];
  }
  __syncthreads();
#pragma unroll
  for (int it = 0; it < 4; ++it) {
    int cj = it * 256 + tid;                  // 1024 16B chunks: 128 d x 8 sc
    int d = cj >> 3, scx = cj & 7;
    bf16x8 vv = *(const bf16x8*)(tile + d * 72 + scx * 8);
    *(bf16x8*)(Vt + ((size_t)bh * HD + d) * S_ + s0 + scx * 8) = vv;
  }
}

// ---------------- flash attention v3 ----------------
// 128 threads (2 waves), 64 q-rows/block (32/wave), 64-key chunks.
// Q (BH,Sq,128) bf16 scale-baked; K (BH,Sk,128); V (BH,128,Sk); Y (B,Sq,2048) bf16
__global__ __launch_bounds__(128) void flash(const unsigned short* __restrict__ Q,
                                             const unsigned short* __restrict__ Kt,
                                             const unsigned short* __restrict__ Vt,
                                             unsigned short* __restrict__ Y) {
  __shared__ unsigned short lK[64 * HD];      // [key][dim], chunk-swizzled
  __shared__ unsigned short lV[HD * 64];      // [dim][key], chunk-swizzled
  __shared__ unsigned short lP[2 * 1024];     // per-wave P scratch (reused per half)
  const int tid = threadIdx.x, wave = tid >> 6, lane = tid & 63;
  const int quad = lane >> 4, l16 = lane & 15;
  const int qb = blockIdx.x & 31;   // Sq/64
  const int bh = blockIdx.x >> 5;
  const int b = bh >> 4, h = bh & 15;
  const int q0 = qb * 64 + wave * 32;

  bf16x8 aq[2][4];
#pragma unroll
  for (int u = 0; u < 2; u++) {
    const unsigned short* qrow = Q + ((size_t)bh * S_ + q0 + u * 16 + l16) * HD;
#pragma unroll
    for (int t = 0; t < 4; t++) aq[u][t] = *(const bf16x8*)(qrow + t * 32 + quad * 8);
  }
  f32x4 o[2][8];
#pragma unroll
  for (int u = 0; u < 2; u++)
#pragma unroll
    for (int t = 0; t < 8; t++) o[u][t] = (f32x4){0.f, 0.f, 0.f, 0.f};
  float lsum[2][4] = {{0.f, 0.f, 0.f, 0.f}, {0.f, 0.f, 0.f, 0.f}};

  const unsigned short* kbase = Kt + (size_t)bh * S_ * HD;
  const unsigned short* vbase = Vt + (size_t)bh * HD * S_;
  unsigned short* lPw = lP + wave * 1024;
  const int mrow = quad * 4;
  const int xsl = (l16 >> 1) & 3;    // P-read swizzle (4 chunks per 32-key row)
  const int xsl7 = (l16 >> 1) & 7;   // V-read swizzle (8 chunks per 64-key row)

  for (int k0 = 0; k0 < S_; k0 += 64) {
    __syncthreads();
#pragma unroll
    for (int call = 0; call < 8; ++call) {
      int c = call * 128 + wave * 64 + lane;  // 1024 chunks of 16B each
      int key = c >> 4, sk = c & 15;          // K: 64 keys x 16 dim-chunks
      int dck = sk ^ (key & 15);
      __builtin_amdgcn_global_load_lds(AS1(kbase + (size_t)(k0 + key) * HD + dck * 8),
                                       AS3(lK + (call * 128 + wave * 64) * 8), 16, 0, 0);
      int dv = c >> 3, sv = c & 7;            // V: 128 dims x 8 key-chunks
      int kc = sv ^ ((dv >> 1) & 7);
      __builtin_amdgcn_global_load_lds(AS1(vbase + (size_t)dv * S_ + k0 + kc * 8),
                                       AS3(lV + (call * 128 + wave * 64) * 8), 16, 0, 0);
    }
    __syncthreads();

#pragma unroll
    for (int h2 = 0; h2 < 2; ++h2) {          // two 32-key halves
      // S = Q*K^T  (two 16-key tiles x two 16-row q subtiles; K frags shared)
      f32x4 s0[2] = {(f32x4){0.f, 0.f, 0.f, 0.f}, (f32x4){0.f, 0.f, 0.f, 0.f}};
      f32x4 s1[2] = {(f32x4){0.f, 0.f, 0.f, 0.f}, (f32x4){0.f, 0.f, 0.f, 0.f}};
      {
        const unsigned short* krow0 = lK + (h2 * 32 + l16) * HD;
        const unsigned short* krow1 = krow0 + 16 * HD;
        __builtin_amdgcn_s_setprio(1);
#pragma unroll
        for (int t = 0; t < 4; t++) {
          int dcq = t * 4 + quad;
          bf16x8 kf0 = *(const bf16x8*)(krow0 + (dcq ^ l16) * 8);
          bf16x8 kf1 = *(const bf16x8*)(krow1 + (dcq ^ l16) * 8);
#pragma unroll
          for (int u = 0; u < 2; u++) {
            s0[u] = __builtin_amdgcn_mfma_f32_16x16x32_bf16(aq[u][t], kf0, s0[u], 0, 0, 0);
            s1[u] = __builtin_amdgcn_mfma_f32_16x16x32_bf16(aq[u][t], kf1, s1[u], 0, 0, 0);
          }
        }
        __builtin_amdgcn_s_setprio(0);
      }
      // softmax numerator (no max subtraction: |s| <= 22.6)
#pragma unroll
      for (int u = 0; u < 2; u++) {
        unsigned short* lPu = lPw + u * 512;
#pragma unroll
        for (int r = 0; r < 4; r++) {
          int m = mrow + r;
          int sx = (m >> 1) & 3;
          float p0 = __expf(s0[u][r]);
          float p1 = __expf(s1[u][r]);
          lsum[u][r] += p0 + p1;
          int kc0 = l16 >> 3;
          lPu[m * 32 + ((kc0 ^ sx)) * 8 + (l16 & 7)] = f2bf(p0);
          lPu[m * 32 + (((kc0 + 2) ^ sx)) * 8 + (l16 & 7)] = f2bf(p1);
        }
      }
      // P: C-layout -> A-layout via LDS (in-wave ordered, no barrier needed)
      bf16x8 pf[2];
#pragma unroll
      for (int u = 0; u < 2; u++)
        pf[u] = *(const bf16x8*)(lPw + u * 512 + l16 * 32 + (quad ^ xsl) * 8);
      // O += P * V  (V frags shared across u)
      __builtin_amdgcn_s_setprio(1);
#pragma unroll
      for (int t = 0; t < 8; t++) {
        bf16x8 vf = *(const bf16x8*)(lV + (t * 16 + l16) * 64 + ((h2 * 4 + quad) ^ xsl7) * 8);
#pragma unroll
        for (int u = 0; u < 2; u++)
          o[u][t] = __builtin_amdgcn_mfma_f32_16x16x32_bf16(pf[u], vf, o[u][t], 0, 0, 0);
      }
      __builtin_amdgcn_s_setprio(0);
    }
  }

  // reduce row-sums across the 16 lanes of each quad
#pragma unroll
  for (int off = 1; off < 16; off <<= 1) {
#pragma unroll
    for (int u = 0; u < 2; u++)
#pragma unroll
      for (int r = 0; r < 4; r++) lsum[u][r] += __shfl_xor(lsum[u][r], off);
  }
  float inv[2][4];
#pragma unroll
  for (int u = 0; u < 2; u++)
#pragma unroll
    for (int r = 0; r < 4; r++) inv[u][r] = 1.0f / lsum[u][r];
#pragma unroll
  for (int u = 0; u < 2; u++)
#pragma unroll
    for (int t = 0; t < 8; t++)
#pragma unroll
      for (int r = 0; r < 4; r++) {
        size_t idx = ((size_t)b * S_ + q0 + u * 16 + mrow + r) * DM + h * HD + t * 16 + l16;
        Y[idx] = f2bf(o[u][t][r] * inv[u][r]);
      }
}

// ============================================================================
extern "C" void kernel_launch(void* const* d_in, const int* in_sizes, int n_in,
                              void* d_out, int out_size, void* d_ws, size_t ws_size,
                              hipStream_t stream) {
  const float* x    = (const float*)d_in[0];
  const float* ctx  = (const float*)d_in[1];
  const float* cosq = (const float*)d_in[2];
  const float* sinq = (const float*)d_in[3];
  const float* cosk = (const float*)d_in[4];
  const float* sink = (const float*)d_in[5];
  const float* Wq   = (const float*)d_in[6];
  const float* Wk   = (const float*)d_in[7];
  const float* Wv   = (const float*)d_in[8];
  const float* Wo   = (const float*)d_in[9];
  const float* qw   = (const float*)d_in[10];
  const float* kw   = (const float*)d_in[11];

  // ---- workspace layout with lifetime overlap (~118 MB) ----
  char* ws = (char*)d_ws;
  const size_t ACT2 = (size_t)M_ * DM * 2;   // 16.8 MB bf16 activation
  const size_t W2   = (size_t)DM * DM * 2;   // 8.4 MB bf16 weight
  unsigned short* xb  = (unsigned short*)(ws);                    // -> qn
  unsigned short* cb  = (unsigned short*)(ws + ACT2);             // -> vt
  unsigned short* Wqb = (unsigned short*)(ws + 2 * ACT2);         // \ kn
  unsigned short* Wkb = (unsigned short*)(ws + 2 * ACT2 + W2);    // /
  unsigned short* Wvb = (unsigned short*)(ws + 2 * ACT2 + 2 * W2);
  unsigned short* Wob = (unsigned short*)(ws + 2 * ACT2 + 3 * W2);
  unsigned short* Pq  = (unsigned short*)(ws + 2 * ACT2 + 4 * W2);  // -> yb
  unsigned short* Pk  = (unsigned short*)(ws + 3 * ACT2 + 4 * W2);
  unsigned short* Pv  = (unsigned short*)(ws + 4 * ACT2 + 4 * W2);
  unsigned short* qn = xb;          // after gemm_qkv consumed xb
  unsigned short* kn = Wqb;         // spans Wqb+Wkb, dead after gemm_qkv
  unsigned short* vt = cb;          // after gemm_qkv consumed cb
  unsigned short* yb = Pq;          // after normrope consumed Pq

  const float scale = 0.0883883476483184f;  // 1/sqrt(128)

  castbf<<<M_ * DM / 1024, 256, 0, stream>>>(x, xb, M_ * DM / 4);
  castbf<<<M_ * DM / 1024, 256, 0, stream>>>(ctx, cb, M_ * DM / 4);
  castbf<<<DM * DM / 1024, 256, 0, stream>>>(Wq, Wqb, DM * DM / 4);
  castbf<<<DM * DM / 1024, 256, 0, stream>>>(Wk, Wkb, DM * DM / 4);
  castbf<<<DM * DM / 1024, 256, 0, stream>>>(Wv, Wvb, DM * DM / 4);
  castbf<<<DM * DM / 1024, 256, 0, stream>>>(Wo, Wob, DM * DM / 4);

  dim3 gq(M_ / 256, DM / 128, 3);   // 16 x 16 x 3 = 768 blocks = 3 full CU-rounds
  gemm_qkv<<<gq, 512, 0, stream>>>(xb, cb, Wqb, Wkb, Wvb, Pq, Pk, Pv);

  normrope<<<M_ * H_ / 4, 256, 0, stream>>>(Pq, cosq, sinq, qw, qn, scale);
  normrope<<<M_ * H_ / 4, 256, 0, stream>>>(Pk, cosk, sink, kw, kn, 1.0f);
  vtrans<<<B_ * H_ * (S_ / 64), 256, 0, stream>>>(Pv, vt);

  flash<<<B_ * H_ * (S_ / 64), 128, 0, stream>>>(qn, kn, vt, yb);

  dim3 gg(M_ / 256, DM / 128);      // 16 x 16 = 256 blocks = 1 full CU-round
  gemm_bt<<<gg, 512, 0, stream>>>(yb, Wob, (float*)d_out);

  (void)in_sizes; (void)n_in; (void)out_size; (void)ws_size;
}

// Round 3
// 478.077 us; speedup vs baseline: 1.0442x; 1.0109x over previous
//
#include <hip/hip_runtime.h>

// ============================================================================
// AdapterAttention on gfx950.
// R5: density fix. R3/R4 post-mortem: MfmaUtil pinned at ~36% across three
//     schedules because wave-tile 64x64 = 32 MFMA/K64/wave is only ~41% of the
//     ~3000-cyc K-tile wall. This round: wave-tile 128x64 (m201 density,
//     64 MFMA/K64/wave), BM=128 BN=256 BK=32, 4 waves, 2 blocks/CU (72 KB
//     ring-3 LDS x2 = 144 KB), counted vmcnt(6), 1 barrier/K-step, two
//     independent barrier domains per CU. Two-rows-per-128B-line LDS packing
//     keeps the verified conflict-free 8-chunk XOR swizzle at BK=32.
//     Grids: qkv 32x8x3=768, bt 32x8=256.
// ============================================================================

typedef __attribute__((ext_vector_type(8))) short bf16x8;
typedef __attribute__((ext_vector_type(4))) float f32x4;

#define AS1(p) ((__attribute__((address_space(1))) void*)(p))
#define AS3(p) ((__attribute__((address_space(3))) void*)(p))
#define STG(g, l) __builtin_amdgcn_global_load_lds(AS1(g), AS3(l), 16, 0, 0)

__device__ __forceinline__ unsigned short f2bf(float f) {
  unsigned int u = __float_as_uint(f);
  u += 0x7fffu + ((u >> 16) & 1u);   // RNE; inputs are finite
  return (unsigned short)(u >> 16);
}
__device__ __forceinline__ float bf2f(unsigned short u) {
  return __uint_as_float(((unsigned int)u) << 16);
}

constexpr int B_ = 2, S_ = 2048, DM = 2048, H_ = 16, HD = 128;
constexpr int M_ = B_ * S_;  // 4096 rows

// ---------------- fp32 -> bf16 cast (vec4) ----------------
__global__ __launch_bounds__(256) void castbf(const float* __restrict__ X,
                                              unsigned short* __restrict__ Y, int n4) {
  int i = blockIdx.x * 256 + threadIdx.x;
  if (i >= n4) return;
  float4 v = ((const float4*)X)[i];
  ushort4 u;
  u.x = f2bf(v.x); u.y = f2bf(v.y); u.z = f2bf(v.z); u.w = f2bf(v.w);
  ((ushort4*)Y)[i] = u;
}

// ---------------- high-density GEMM core: C = A * W^T -----------------------
// BM=128, BN=256, BK=32. 256 threads = 4 waves (1M x 4N); wave-tile 128x64 =
// 8x4 fragments = 32 MFMA per K-step-32 per wave (m201 density).
// LDS ring: 3 slots x 24 KB (A 8 KB + B 16 KB) = 72 KB -> 2 blocks/CU.
// LDS packing: line L (128 B, 8 chunks of 16 B) holds tile rows {L, L+64} (A)
// / {L, L+128} (B), k-chunks 0..3 each; chunk at phys = j ^ (L&7) where
// logical j = (rowhalf<<2)|kchunk. Staged via pre-swizzled per-lane global
// sources (global_load_lds dest = wave-uniform base + lane*16, linear).
// Per K-step: 12 ds_read_b128 + 6 global_load_lds (tile t+2 -> slot (t+2)%3)
// + gate vmcnt(6) + 1 barrier + 32 MFMA. No drain until the last two steps.
template <int BF16OUT>
__device__ __forceinline__ void gemm_core(const unsigned short* __restrict__ A,
                                          const unsigned short* __restrict__ Bw,
                                          void* __restrict__ Cv,
                                          unsigned short* lds) {
  const int tid = threadIdx.x, wave = tid >> 6, lane = tid & 63;
  const int quad = lane >> 4, l16 = lane & 15;
  const int m0 = blockIdx.x * 128, n0 = blockIdx.y * 256;
  const int wn = wave * 64;
  constexpr int NT = DM / 32;     // 64 K-steps
  constexpr int SLOT = 12288;     // shorts per ring slot (24 KB)

  f32x4 acc[8][4];
#pragma unroll
  for (int f = 0; f < 8; f++)
#pragma unroll
    for (int g = 0; g < 4; g++) acc[f][g] = (f32x4){0.f, 0.f, 0.f, 0.f};

  // -- staging sources (per-lane, pre-swizzled). Chunk c: L=c>>3, phys=c&7,
  //    j = phys ^ (L&7); stored element = row (L + rowhalf*{64|128}),
  //    k-chunk j&3. LDS dest is linear: offset c*8 shorts.
  const unsigned short* srcA[2];
  const unsigned short* srcB[4];
#pragma unroll
  for (int i = 0; i < 2; i++) {
    int c = tid + i * 256, L = c >> 3, ph = c & 7, j = ph ^ (L & 7);
    srcA[i] = A + (size_t)(m0 + L + ((j >> 2) << 6)) * DM + (j & 3) * 8;
  }
#pragma unroll
  for (int i = 0; i < 4; i++) {
    int c = tid + i * 256, L = c >> 3, ph = c & 7, j = ph ^ (L & 7);
    srcB[i] = Bw + (size_t)(n0 + L + ((j >> 2) << 7)) * DM + (j & 3) * 8;
  }

#define STAGEK(T, S)                                                           \
  { const int ko = (T) << 5; unsigned short* lb = lds + (S) * SLOT + wave * 512;\
    STG(srcA[0] + ko, lb);                                                     \
    STG(srcA[1] + ko, lb + 2048);                                              \
    STG(srcB[0] + ko, lb + 4096);                                              \
    STG(srcB[1] + ko, lb + 6144);                                              \
    STG(srcB[2] + ko, lb + 8192);                                              \
    STG(srcB[3] + ko, lb + 10240); }

  // -- read-side offsets (shorts). A frag f: row r=f*16+l16, line L=r&63,
  //    j = ((f>>2)<<2)|quad, phys = j^(l16&7). B frag g: row rb=wn+g*16+l16,
  //    line L=rb&127, j = ((wave>>1)<<2)|quad.
  const int x8 = l16 & 7;
  const int ab0 = l16 * 64 + ((quad ^ x8)) * 8;            // A frags 0..3
  const int ab1 = l16 * 64 + (((4 | quad) ^ x8)) * 8;      // A frags 4..7
  const int bb  = 4096 + (wn & 64) * 64 + l16 * 64 +
                  ((((wave >> 1) << 2) | quad) ^ x8) * 8;  // B frags (+g*1024)

  // -- prologue: stage tiles 0,1; gate tile 0 (tile 1's 6 stay in flight) --
  STAGEK(0, 0) STAGEK(1, 1)
  asm volatile("s_waitcnt vmcnt(6)" ::: "memory");
  __builtin_amdgcn_s_barrier();

  int st = 0, s2 = 2;
  for (int t = 0; t < NT; ++t) {
    const unsigned short* ls = lds + st * SLOT;
    bf16x8 af[8], bfv[4];
#pragma unroll
    for (int f = 0; f < 4; f++) af[f]     = *(const bf16x8*)(ls + f * 1024 + ab0);
#pragma unroll
    for (int f = 0; f < 4; f++) af[f + 4] = *(const bf16x8*)(ls + f * 1024 + ab1);
#pragma unroll
    for (int g = 0; g < 4; g++) bfv[g]    = *(const bf16x8*)(ls + g * 1024 + bb);

    if (t + 2 < NT) STAGEK(t + 2, s2)
    // gate: tile t+1 landed; tile t+2's 6 loads stay in flight (no drain)
    if (t < NT - 2)       asm volatile("s_waitcnt vmcnt(6)" ::: "memory");
    else if (t == NT - 2) asm volatile("s_waitcnt vmcnt(0)" ::: "memory");
    if (t < NT - 1) __builtin_amdgcn_s_barrier();

    __builtin_amdgcn_s_setprio(1);
#pragma unroll
    for (int f = 0; f < 8; f++)
#pragma unroll
      for (int g = 0; g < 4; g++)
        acc[f][g] = __builtin_amdgcn_mfma_f32_16x16x32_bf16(af[f], bfv[g], acc[f][g], 0, 0, 0);
    __builtin_amdgcn_s_setprio(0);

    st++; if (st == 3) st = 0;
    s2++; if (s2 == 3) s2 = 0;
  }
#undef STAGEK

  // ---- epilogue: C write ----
#pragma unroll
  for (int f = 0; f < 8; f++)
#pragma unroll
    for (int g = 0; g < 4; g++) {
      const size_t row = (size_t)(m0 + f * 16 + quad * 4);
      const int col = n0 + wn + g * 16 + l16;
      if (BF16OUT) {
        unsigned short* cp = (unsigned short*)Cv + row * DM + col;
#pragma unroll
        for (int r = 0; r < 4; r++) cp[(size_t)r * DM] = f2bf(acc[f][g][r]);
      } else {
        float* cp = (float*)Cv + row * DM + col;
#pragma unroll
        for (int r = 0; r < 4; r++) cp[(size_t)r * DM] = acc[f][g][r];
      }
    }
}

// ---------------- batched QKV GEMM: P[z] = A[z] * W[z]^T, bf16 out ----------
__global__ __launch_bounds__(256, 2) void gemm_qkv(const unsigned short* __restrict__ xb,
                                                   const unsigned short* __restrict__ cb,
                                                   const unsigned short* __restrict__ Wq,
                                                   const unsigned short* __restrict__ Wk,
                                                   const unsigned short* __restrict__ Wv,
                                                   unsigned short* __restrict__ Pq,
                                                   unsigned short* __restrict__ Pk,
                                                   unsigned short* __restrict__ Pv) {
  __shared__ __align__(16) unsigned short lds[3 * 12288];  // 72 KiB
  const int z = blockIdx.z;
  const unsigned short* A  = (z == 0) ? xb : cb;
  const unsigned short* Bw = (z == 0) ? Wq : (z == 1) ? Wk : Wv;
  unsigned short* C        = (z == 0) ? Pq : (z == 1) ? Pk : Pv;
  gemm_core<1>(A, Bw, C, lds);
}

// ---------------- bf16 GEMM: C = A * W^T (fp32 out), for out-proj -----------
__global__ __launch_bounds__(256, 2) void gemm_bt(const unsigned short* __restrict__ A,
                                                  const unsigned short* __restrict__ Bw,
                                                  float* __restrict__ C) {
  __shared__ __align__(16) unsigned short lds[3 * 12288];  // 72 KiB
  gemm_core<0>(A, Bw, C, lds);
}

// ---------------- fused RMSNorm + RoPE, bf16 (B,S,H,hd) -> (B,H,S,hd) bf16 --
__global__ __launch_bounds__(256) void normrope(const unsigned short* __restrict__ X,
                                                const float* __restrict__ Cs,
                                                const float* __restrict__ Sn,
                                                const float* __restrict__ W,
                                                unsigned short* __restrict__ Out,
                                                float scale) {
  int gw = (blockIdx.x * 256 + threadIdx.x) >> 6;  // (b*S+s)*H + h
  int lane = threadIdx.x & 63;
  int h = gw & 15, bs = gw >> 4;          // bs = b*S + s
  int s = bs & (S_ - 1), b = bs >> 11;
  const unsigned short* xr = X + (size_t)gw * HD;
  float x0 = bf2f(xr[lane]), x1 = bf2f(xr[lane + 64]);
  float ss = x0 * x0 + x1 * x1;
#pragma unroll
  for (int off = 32; off > 0; off >>= 1) ss += __shfl_xor(ss, off);
  float rr = rsqrtf(ss * (1.0f / 128.0f) + 1e-6f);
  float n0 = x0 * rr * W[lane], n1 = x1 * rr * W[lane + 64];
  const float* cp = Cs + (size_t)bs * HD;
  const float* sp = Sn + (size_t)bs * HD;
  float o0 = (n0 * cp[lane] - n1 * sp[lane]) * scale;
  float o1 = (n1 * cp[lane + 64] + n0 * sp[lane + 64]) * scale;
  unsigned short* orow = Out + (((size_t)(b * H_ + h)) * S_ + s) * HD;
  orow[lane] = f2bf(o0);
  orow[lane + 64] = f2bf(o1);
}

// ---------------- V: bf16 (B,S,H,hd) -> (B*H, hd, Sk) bf16 (transposed) -----
__global__ __launch_bounds__(256) void vtrans(const unsigned short* __restrict__ Vf,
                                              unsigned short* __restrict__ Vt) {
  __shared__ unsigned short tile[128 * 72];  // [d][s], stride 72
  const int tid = threadIdx.x;
  const int sc = blockIdx.x & 31;
  const int bh = blockIdx.x >> 5;
  const int b = bh >> 4, h = bh & 15;
  const int s0 = sc * 64;
#pragma unroll
  for (int it = 0; it < 4; ++it) {
    int ci = it * 256 + tid;                  // 1024 chunks: 64 s x 16 dc
    int s = ci >> 4, dc = ci & 15;
    bf16x8 v = *(const bf16x8*)(Vf + ((size_t)(b * S_ + s0 + s)) * DM + h * HD + dc * 8);
    unsigned short* tp = tile + (dc * 8) * 72 + s;
#pragma unroll
    for (int e = 0; e < 8; e++) tp[e * 72] = (unsigned short)v[e];
  }
  __syncthreads();
#pragma unroll
  for (int it = 0; it < 4; ++it) {
    int cj = it * 256 + tid;                  // 1024 16B chunks: 128 d x 8 sc
    int d = cj >> 3, scx = cj & 7;
    bf16x8 vv = *(const bf16x8*)(tile + d * 72 + scx * 8);
    *(bf16x8*)(Vt + ((size_t)bh * HD + d) * S_ + s0 + scx * 8) = vv;
  }
}

// ---------------- flash attention v3 ----------------
// 128 threads (2 waves), 64 q-rows/block (32/wave), 64-key chunks.
// Q (BH,Sq,128) bf16 scale-baked; K (BH,Sk,128); V (BH,128,Sk); Y (B,Sq,2048) bf16
__global__ __launch_bounds__(128) void flash(const unsigned short* __restrict__ Q,
                                             const unsigned short* __restrict__ Kt,
                                             const unsigned short* __restrict__ Vt,
                                             unsigned short* __restrict__ Y) {
  __shared__ unsigned short lK[64 * HD];      // [key][dim], chunk-swizzled
  __shared__ unsigned short lV[HD * 64];      // [dim][key], chunk-swizzled
  __shared__ unsigned short lP[2 * 1024];     // per-wave P scratch (reused per half)
  const int tid = threadIdx.x, wave = tid >> 6, lane = tid & 63;
  const int quad = lane >> 4, l16 = lane & 15;
  const int qb = blockIdx.x & 31;   // Sq/64
  const int bh = blockIdx.x >> 5;
  const int b = bh >> 4, h = bh & 15;
  const int q0 = qb * 64 + wave * 32;

  bf16x8 aq[2][4];
#pragma unroll
  for (int u = 0; u < 2; u++) {
    const unsigned short* qrow = Q + ((size_t)bh * S_ + q0 + u * 16 + l16) * HD;
#pragma unroll
    for (int t = 0; t < 4; t++) aq[u][t] = *(const bf16x8*)(qrow + t * 32 + quad * 8);
  }
  f32x4 o[2][8];
#pragma unroll
  for (int u = 0; u < 2; u++)
#pragma unroll
    for (int t = 0; t < 8; t++) o[u][t] = (f32x4){0.f, 0.f, 0.f, 0.f};
  float lsum[2][4] = {{0.f, 0.f, 0.f, 0.f}, {0.f, 0.f, 0.f, 0.f}};

  const unsigned short* kbase = Kt + (size_t)bh * S_ * HD;
  const unsigned short* vbase = Vt + (size_t)bh * HD * S_;
  unsigned short* lPw = lP + wave * 1024;
  const int mrow = quad * 4;
  const int xsl = (l16 >> 1) & 3;    // P-read swizzle (4 chunks per 32-key row)
  const int xsl7 = (l16 >> 1) & 7;   // V-read swizzle (8 chunks per 64-key row)

  for (int k0 = 0; k0 < S_; k0 += 64) {
    __syncthreads();
#pragma unroll
    for (int call = 0; call < 8; ++call) {
      int c = call * 128 + wave * 64 + lane;  // 1024 chunks of 16B each
      int key = c >> 4, sk = c & 15;          // K: 64 keys x 16 dim-chunks
      int dck = sk ^ (key & 15);
      __builtin_amdgcn_global_load_lds(AS1(kbase + (size_t)(k0 + key) * HD + dck * 8),
                                       AS3(lK + (call * 128 + wave * 64) * 8), 16, 0, 0);
      int dv = c >> 3, sv = c & 7;            // V: 128 dims x 8 key-chunks
      int kc = sv ^ ((dv >> 1) & 7);
      __builtin_amdgcn_global_load_lds(AS1(vbase + (size_t)dv * S_ + k0 + kc * 8),
                                       AS3(lV + (call * 128 + wave * 64) * 8), 16, 0, 0);
    }
    __syncthreads();

#pragma unroll
    for (int h2 = 0; h2 < 2; ++h2) {          // two 32-key halves
      // S = Q*K^T  (two 16-key tiles x two 16-row q subtiles; K frags shared)
      f32x4 s0[2] = {(f32x4){0.f, 0.f, 0.f, 0.f}, (f32x4){0.f, 0.f, 0.f, 0.f}};
      f32x4 s1[2] = {(f32x4){0.f, 0.f, 0.f, 0.f}, (f32x4){0.f, 0.f, 0.f, 0.f}};
      {
        const unsigned short* krow0 = lK + (h2 * 32 + l16) * HD;
        const unsigned short* krow1 = krow0 + 16 * HD;
        __builtin_amdgcn_s_setprio(1);
#pragma unroll
        for (int t = 0; t < 4; t++) {
          int dcq = t * 4 + quad;
          bf16x8 kf0 = *(const bf16x8*)(krow0 + (dcq ^ l16) * 8);
          bf16x8 kf1 = *(const bf16x8*)(krow1 + (dcq ^ l16) * 8);
#pragma unroll
          for (int u = 0; u < 2; u++) {
            s0[u] = __builtin_amdgcn_mfma_f32_16x16x32_bf16(aq[u][t], kf0, s0[u], 0, 0, 0);
            s1[u] = __builtin_amdgcn_mfma_f32_16x16x32_bf16(aq[u][t], kf1, s1[u], 0, 0, 0);
          }
        }
        __builtin_amdgcn_s_setprio(0);
      }
      // softmax numerator (no max subtraction: |s| <= 22.6)
#pragma unroll
      for (int u = 0; u < 2; u++) {
        unsigned short* lPu = lPw + u * 512;
#pragma unroll
        for (int r = 0; r < 4; r++) {
          int m = mrow + r;
          int sx = (m >> 1) & 3;
          float p0 = __expf(s0[u][r]);
          float p1 = __expf(s1[u][r]);
          lsum[u][r] += p0 + p1;
          int kc0 = l16 >> 3;
          lPu[m * 32 + ((kc0 ^ sx)) * 8 + (l16 & 7)] = f2bf(p0);
          lPu[m * 32 + (((kc0 + 2) ^ sx)) * 8 + (l16 & 7)] = f2bf(p1);
        }
      }
      // P: C-layout -> A-layout via LDS (in-wave ordered, no barrier needed)
      bf16x8 pf[2];
#pragma unroll
      for (int u = 0; u < 2; u++)
        pf[u] = *(const bf16x8*)(lPw + u * 512 + l16 * 32 + (quad ^ xsl) * 8);
      // O += P * V  (V frags shared across u)
      __builtin_amdgcn_s_setprio(1);
#pragma unroll
      for (int t = 0; t < 8; t++) {
        bf16x8 vf = *(const bf16x8*)(lV + (t * 16 + l16) * 64 + ((h2 * 4 + quad) ^ xsl7) * 8);
#pragma unroll
        for (int u = 0; u < 2; u++)
          o[u][t] = __builtin_amdgcn_mfma_f32_16x16x32_bf16(pf[u], vf, o[u][t], 0, 0, 0);
      }
      __builtin_amdgcn_s_setprio(0);
    }
  }

  // reduce row-sums across the 16 lanes of each quad
#pragma unroll
  for (int off = 1; off < 16; off <<= 1) {
#pragma unroll
    for (int u = 0; u < 2; u++)
#pragma unroll
      for (int r = 0; r < 4; r++) lsum[u][r] += __shfl_xor(lsum[u][r], off);
  }
  float inv[2][4];
#pragma unroll
  for (int u = 0; u < 2; u++)
#pragma unroll
    for (int r = 0; r < 4; r++) inv[u][r] = 1.0f / lsum[u][r];
#pragma unroll
  for (int u = 0; u < 2; u++)
#pragma unroll
    for (int t = 0; t < 8; t++)
#pragma unroll
      for (int r = 0; r < 4; r++) {
        size_t idx = ((size_t)b * S_ + q0 + u * 16 + mrow + r) * DM + h * HD + t * 16 + l16;
        Y[idx] = f2bf(o[u][t][r] * inv[u][r]);
      }
}

// ============================================================================
extern "C" void kernel_launch(void* const* d_in, const int* in_sizes, int n_in,
                              void* d_out, int out_size, void* d_ws, size_t ws_size,
                              hipStream_t stream) {
  const float* x    = (const float*)d_in[0];
  const float* ctx  = (const float*)d_in[1];
  const float* cosq = (const float*)d_in[2];
  const float* sinq = (const float*)d_in[3];
  const float* cosk = (const float*)d_in[4];
  const float* sink = (const float*)d_in[5];
  const float* Wq   = (const float*)d_in[6];
  const float* Wk   = (const float*)d_in[7];
  const float* Wv   = (const float*)d_in[8];
  const float* Wo   = (const float*)d_in[9];
  const float* qw   = (const float*)d_in[10];
  const float* kw   = (const float*)d_in[11];

  // ---- workspace layout with lifetime overlap (~118 MB) ----
  char* ws = (char*)d_ws;
  const size_t ACT2 = (size_t)M_ * DM * 2;   // 16.8 MB bf16 activation
  const size_t W2   = (size_t)DM * DM * 2;   // 8.4 MB bf16 weight
  unsigned short* xb  = (unsigned short*)(ws);                    // -> qn
  unsigned short* cb  = (unsigned short*)(ws + ACT2);             // -> vt
  unsigned short* Wqb = (unsigned short*)(ws + 2 * ACT2);         // \ kn
  unsigned short* Wkb = (unsigned short*)(ws + 2 * ACT2 + W2);    // /
  unsigned short* Wvb = (unsigned short*)(ws + 2 * ACT2 + 2 * W2);
  unsigned short* Wob = (unsigned short*)(ws + 2 * ACT2 + 3 * W2);
  unsigned short* Pq  = (unsigned short*)(ws + 2 * ACT2 + 4 * W2);  // -> yb
  unsigned short* Pk  = (unsigned short*)(ws + 3 * ACT2 + 4 * W2);
  unsigned short* Pv  = (unsigned short*)(ws + 4 * ACT2 + 4 * W2);
  unsigned short* qn = xb;          // after gemm_qkv consumed xb
  unsigned short* kn = Wqb;         // spans Wqb+Wkb, dead after gemm_qkv
  unsigned short* vt = cb;          // after gemm_qkv consumed cb
  unsigned short* yb = Pq;          // after normrope consumed Pq

  const float scale = 0.0883883476483184f;  // 1/sqrt(128)

  castbf<<<M_ * DM / 1024, 256, 0, stream>>>(x, xb, M_ * DM / 4);
  castbf<<<M_ * DM / 1024, 256, 0, stream>>>(ctx, cb, M_ * DM / 4);
  castbf<<<DM * DM / 1024, 256, 0, stream>>>(Wq, Wqb, DM * DM / 4);
  castbf<<<DM * DM / 1024, 256, 0, stream>>>(Wk, Wkb, DM * DM / 4);
  castbf<<<DM * DM / 1024, 256, 0, stream>>>(Wv, Wvb, DM * DM / 4);
  castbf<<<DM * DM / 1024, 256, 0, stream>>>(Wo, Wob, DM * DM / 4);

  dim3 gq(M_ / 128, DM / 256, 3);   // 32 x 8 x 3 = 768 blocks (2 per CU)
  gemm_qkv<<<gq, 256, 0, stream>>>(xb, cb, Wqb, Wkb, Wvb, Pq, Pk, Pv);

  normrope<<<M_ * H_ / 4, 256, 0, stream>>>(Pq, cosq, sinq, qw, qn, scale);
  normrope<<<M_ * H_ / 4, 256, 0, stream>>>(Pk, cosk, sink, kw, kn, 1.0f);
  vtrans<<<B_ * H_ * (S_ / 64), 256, 0, stream>>>(Pv, vt);

  flash<<<B_ * H_ * (S_ / 64), 128, 0, stream>>>(qn, kn, vt, yb);

  dim3 gg(M_ / 128, DM / 256);      // 32 x 8 = 256 blocks
  gemm_bt<<<gg, 256, 0, stream>>>(yb, Wob, (float*)d_out);

  (void)in_sizes; (void)n_in; (void)out_size; (void)ws_size;
}

// Round 4
// 457.422 us; speedup vs baseline: 1.0913x; 1.0452x over previous
//
#include <hip/hip_runtime.h>

// ============================================================================
// AdapterAttention on gfx950.
// R6: flash de-drained. R5 left flash as the #1 dispatch (116us, MfmaUtil 25%,
//     nothing saturated): it still had the m97 disease — __syncthreads / issue
//     16 loads / __syncthreads(=vmcnt(0) drain) / compute, every 64-key iter.
//     Now: K/V double-buffer (2x16KB each), counted s_waitcnt vmcnt(8) gates
//     (stage t+1 during compute of t; no drain until last iter), raw
//     s_barriers, and Q-tile 128/block (4 waves, 256 thr) halving per-thread
//     staging issue and K/V logical traffic. Grid 512 = exactly 2 blocks/CU
//     (72KB LDS x2 = 144 <= 160). GEMMs unchanged from R5 (BM=128 BN=256
//     BK=32, wave-tile 128x64, ring-3, vmcnt(6), 2 blocks/CU).
// ============================================================================

typedef __attribute__((ext_vector_type(8))) short bf16x8;
typedef __attribute__((ext_vector_type(4))) float f32x4;

#define AS1(p) ((__attribute__((address_space(1))) void*)(p))
#define AS3(p) ((__attribute__((address_space(3))) void*)(p))
#define STG(g, l) __builtin_amdgcn_global_load_lds(AS1(g), AS3(l), 16, 0, 0)

__device__ __forceinline__ unsigned short f2bf(float f) {
  unsigned int u = __float_as_uint(f);
  u += 0x7fffu + ((u >> 16) & 1u);   // RNE; inputs are finite
  return (unsigned short)(u >> 16);
}
__device__ __forceinline__ float bf2f(unsigned short u) {
  return __uint_as_float(((unsigned int)u) << 16);
}

constexpr int B_ = 2, S_ = 2048, DM = 2048, H_ = 16, HD = 128;
constexpr int M_ = B_ * S_;  // 4096 rows

// ---------------- fp32 -> bf16 cast (vec4) ----------------
__global__ __launch_bounds__(256) void castbf(const float* __restrict__ X,
                                              unsigned short* __restrict__ Y, int n4) {
  int i = blockIdx.x * 256 + threadIdx.x;
  if (i >= n4) return;
  float4 v = ((const float4*)X)[i];
  ushort4 u;
  u.x = f2bf(v.x); u.y = f2bf(v.y); u.z = f2bf(v.z); u.w = f2bf(v.w);
  ((ushort4*)Y)[i] = u;
}

// ---------------- high-density GEMM core: C = A * W^T -----------------------
// BM=128, BN=256, BK=32. 256 threads = 4 waves (1M x 4N); wave-tile 128x64 =
// 8x4 fragments = 32 MFMA per K-step-32 per wave (m201 density).
// LDS ring: 3 slots x 24 KB (A 8 KB + B 16 KB) = 72 KB -> 2 blocks/CU.
// LDS packing: line L (128 B, 8 chunks of 16 B) holds tile rows {L, L+64} (A)
// / {L, L+128} (B), k-chunks 0..3 each; chunk at phys = j ^ (L&7) where
// logical j = (rowhalf<<2)|kchunk. Staged via pre-swizzled per-lane global
// sources (global_load_lds dest = wave-uniform base + lane*16, linear).
// Per K-step: 12 ds_read_b128 + 6 global_load_lds (tile t+2 -> slot (t+2)%3)
// + gate vmcnt(6) + 1 barrier + 32 MFMA. No drain until the last two steps.
template <int BF16OUT>
__device__ __forceinline__ void gemm_core(const unsigned short* __restrict__ A,
                                          const unsigned short* __restrict__ Bw,
                                          void* __restrict__ Cv,
                                          unsigned short* lds) {
  const int tid = threadIdx.x, wave = tid >> 6, lane = tid & 63;
  const int quad = lane >> 4, l16 = lane & 15;
  const int m0 = blockIdx.x * 128, n0 = blockIdx.y * 256;
  const int wn = wave * 64;
  constexpr int NT = DM / 32;     // 64 K-steps
  constexpr int SLOT = 12288;     // shorts per ring slot (24 KB)

  f32x4 acc[8][4];
#pragma unroll
  for (int f = 0; f < 8; f++)
#pragma unroll
    for (int g = 0; g < 4; g++) acc[f][g] = (f32x4){0.f, 0.f, 0.f, 0.f};

  // -- staging sources (per-lane, pre-swizzled). Chunk c: L=c>>3, phys=c&7,
  //    j = phys ^ (L&7); stored element = row (L + rowhalf*{64|128}),
  //    k-chunk j&3. LDS dest is linear: offset c*8 shorts.
  const unsigned short* srcA[2];
  const unsigned short* srcB[4];
#pragma unroll
  for (int i = 0; i < 2; i++) {
    int c = tid + i * 256, L = c >> 3, ph = c & 7, j = ph ^ (L & 7);
    srcA[i] = A + (size_t)(m0 + L + ((j >> 2) << 6)) * DM + (j & 3) * 8;
  }
#pragma unroll
  for (int i = 0; i < 4; i++) {
    int c = tid + i * 256, L = c >> 3, ph = c & 7, j = ph ^ (L & 7);
    srcB[i] = Bw + (size_t)(n0 + L + ((j >> 2) << 7)) * DM + (j & 3) * 8;
  }

#define STAGEK(T, S)                                                           \
  { const int ko = (T) << 5; unsigned short* lb = lds + (S) * SLOT + wave * 512;\
    STG(srcA[0] + ko, lb);                                                     \
    STG(srcA[1] + ko, lb + 2048);                                              \
    STG(srcB[0] + ko, lb + 4096);                                              \
    STG(srcB[1] + ko, lb + 6144);                                              \
    STG(srcB[2] + ko, lb + 8192);                                              \
    STG(srcB[3] + ko, lb + 10240); }

  // -- read-side offsets (shorts). A frag f: row r=f*16+l16, line L=r&63,
  //    j = ((f>>2)<<2)|quad, phys = j^(l16&7). B frag g: row rb=wn+g*16+l16,
  //    line L=rb&127, j = ((wave>>1)<<2)|quad.
  const int x8 = l16 & 7;
  const int ab0 = l16 * 64 + ((quad ^ x8)) * 8;            // A frags 0..3
  const int ab1 = l16 * 64 + (((4 | quad) ^ x8)) * 8;      // A frags 4..7
  const int bb  = 4096 + (wn & 64) * 64 + l16 * 64 +
                  ((((wave >> 1) << 2) | quad) ^ x8) * 8;  // B frags (+g*1024)

  // -- prologue: stage tiles 0,1; gate tile 0 (tile 1's 6 stay in flight) --
  STAGEK(0, 0) STAGEK(1, 1)
  asm volatile("s_waitcnt vmcnt(6)" ::: "memory");
  __builtin_amdgcn_s_barrier();

  int st = 0, s2 = 2;
  for (int t = 0; t < NT; ++t) {
    const unsigned short* ls = lds + st * SLOT;
    bf16x8 af[8], bfv[4];
#pragma unroll
    for (int f = 0; f < 4; f++) af[f]     = *(const bf16x8*)(ls + f * 1024 + ab0);
#pragma unroll
    for (int f = 0; f < 4; f++) af[f + 4] = *(const bf16x8*)(ls + f * 1024 + ab1);
#pragma unroll
    for (int g = 0; g < 4; g++) bfv[g]    = *(const bf16x8*)(ls + g * 1024 + bb);

    if (t + 2 < NT) STAGEK(t + 2, s2)
    // gate: tile t+1 landed; tile t+2's 6 loads stay in flight (no drain)
    if (t < NT - 2)       asm volatile("s_waitcnt vmcnt(6)" ::: "memory");
    else if (t == NT - 2) asm volatile("s_waitcnt vmcnt(0)" ::: "memory");
    if (t < NT - 1) __builtin_amdgcn_s_barrier();

    __builtin_amdgcn_s_setprio(1);
#pragma unroll
    for (int f = 0; f < 8; f++)
#pragma unroll
      for (int g = 0; g < 4; g++)
        acc[f][g] = __builtin_amdgcn_mfma_f32_16x16x32_bf16(af[f], bfv[g], acc[f][g], 0, 0, 0);
    __builtin_amdgcn_s_setprio(0);

    st++; if (st == 3) st = 0;
    s2++; if (s2 == 3) s2 = 0;
  }
#undef STAGEK

  // ---- epilogue: C write ----
#pragma unroll
  for (int f = 0; f < 8; f++)
#pragma unroll
    for (int g = 0; g < 4; g++) {
      const size_t row = (size_t)(m0 + f * 16 + quad * 4);
      const int col = n0 + wn + g * 16 + l16;
      if (BF16OUT) {
        unsigned short* cp = (unsigned short*)Cv + row * DM + col;
#pragma unroll
        for (int r = 0; r < 4; r++) cp[(size_t)r * DM] = f2bf(acc[f][g][r]);
      } else {
        float* cp = (float*)Cv + row * DM + col;
#pragma unroll
        for (int r = 0; r < 4; r++) cp[(size_t)r * DM] = acc[f][g][r];
      }
    }
}

// ---------------- batched QKV GEMM: P[z] = A[z] * W[z]^T, bf16 out ----------
__global__ __launch_bounds__(256, 2) void gemm_qkv(const unsigned short* __restrict__ xb,
                                                   const unsigned short* __restrict__ cb,
                                                   const unsigned short* __restrict__ Wq,
                                                   const unsigned short* __restrict__ Wk,
                                                   const unsigned short* __restrict__ Wv,
                                                   unsigned short* __restrict__ Pq,
                                                   unsigned short* __restrict__ Pk,
                                                   unsigned short* __restrict__ Pv) {
  __shared__ __align__(16) unsigned short lds[3 * 12288];  // 72 KiB
  const int z = blockIdx.z;
  const unsigned short* A  = (z == 0) ? xb : cb;
  const unsigned short* Bw = (z == 0) ? Wq : (z == 1) ? Wk : Wv;
  unsigned short* C        = (z == 0) ? Pq : (z == 1) ? Pk : Pv;
  gemm_core<1>(A, Bw, C, lds);
}

// ---------------- bf16 GEMM: C = A * W^T (fp32 out), for out-proj -----------
__global__ __launch_bounds__(256, 2) void gemm_bt(const unsigned short* __restrict__ A,
                                                  const unsigned short* __restrict__ Bw,
                                                  float* __restrict__ C) {
  __shared__ __align__(16) unsigned short lds[3 * 12288];  // 72 KiB
  gemm_core<0>(A, Bw, C, lds);
}

// ---------------- fused RMSNorm + RoPE, bf16 (B,S,H,hd) -> (B,H,S,hd) bf16 --
__global__ __launch_bounds__(256) void normrope(const unsigned short* __restrict__ X,
                                                const float* __restrict__ Cs,
                                                const float* __restrict__ Sn,
                                                const float* __restrict__ W,
                                                unsigned short* __restrict__ Out,
                                                float scale) {
  int gw = (blockIdx.x * 256 + threadIdx.x) >> 6;  // (b*S+s)*H + h
  int lane = threadIdx.x & 63;
  int h = gw & 15, bs = gw >> 4;          // bs = b*S + s
  int s = bs & (S_ - 1), b = bs >> 11;
  const unsigned short* xr = X + (size_t)gw * HD;
  float x0 = bf2f(xr[lane]), x1 = bf2f(xr[lane + 64]);
  float ss = x0 * x0 + x1 * x1;
#pragma unroll
  for (int off = 32; off > 0; off >>= 1) ss += __shfl_xor(ss, off);
  float rr = rsqrtf(ss * (1.0f / 128.0f) + 1e-6f);
  float n0 = x0 * rr * W[lane], n1 = x1 * rr * W[lane + 64];
  const float* cp = Cs + (size_t)bs * HD;
  const float* sp = Sn + (size_t)bs * HD;
  float o0 = (n0 * cp[lane] - n1 * sp[lane]) * scale;
  float o1 = (n1 * cp[lane + 64] + n0 * sp[lane + 64]) * scale;
  unsigned short* orow = Out + (((size_t)(b * H_ + h)) * S_ + s) * HD;
  orow[lane] = f2bf(o0);
  orow[lane + 64] = f2bf(o1);
}

// ---------------- V: bf16 (B,S,H,hd) -> (B*H, hd, Sk) bf16 (transposed) -----
__global__ __launch_bounds__(256) void vtrans(const unsigned short* __restrict__ Vf,
                                              unsigned short* __restrict__ Vt) {
  __shared__ unsigned short tile[128 * 72];  // [d][s], stride 72
  const int tid = threadIdx.x;
  const int sc = blockIdx.x & 31;
  const int bh = blockIdx.x >> 5;
  const int b = bh >> 4, h = bh & 15;
  const int s0 = sc * 64;
#pragma unroll
  for (int it = 0; it < 4; ++it) {
    int ci = it * 256 + tid;                  // 1024 chunks: 64 s x 16 dc
    int s = ci >> 4, dc = ci & 15;
    bf16x8 v = *(const bf16x8*)(Vf + ((size_t)(b * S_ + s0 + s)) * DM + h * HD + dc * 8);
    unsigned short* tp = tile + (dc * 8) * 72 + s;
#pragma unroll
    for (int e = 0; e < 8; e++) tp[e * 72] = (unsigned short)v[e];
  }
  __syncthreads();
#pragma unroll
  for (int it = 0; it < 4; ++it) {
    int cj = it * 256 + tid;                  // 1024 16B chunks: 128 d x 8 sc
    int d = cj >> 3, scx = cj & 7;
    bf16x8 vv = *(const bf16x8*)(tile + d * 72 + scx * 8);
    *(bf16x8*)(Vt + ((size_t)bh * HD + d) * S_ + s0 + scx * 8) = vv;
  }
}

// ---------------- flash attention v4 ----------------
// 256 threads (4 waves), 128 q-rows/block (32/wave), 64-key chunks.
// K/V double-buffered (2x16KB each); stage tile t+1 during compute of t;
// counted vmcnt(8) gates (8 loads/thread/tile in flight); raw s_barriers;
// no drain until the final iteration. Grid 512 = exactly 2 blocks/CU.
// Q (BH,Sq,128) bf16 scale-baked; K (BH,Sk,128); V (BH,128,Sk); Y (B,Sq,2048) bf16
__global__ __launch_bounds__(256, 2) void flash(const unsigned short* __restrict__ Q,
                                                const unsigned short* __restrict__ Kt,
                                                const unsigned short* __restrict__ Vt,
                                                unsigned short* __restrict__ Y) {
  __shared__ unsigned short lK[2 * 64 * HD];  // [buf][key][dim], chunk-swizzled
  __shared__ unsigned short lV[2 * HD * 64];  // [buf][dim][key], chunk-swizzled
  __shared__ unsigned short lP[4 * 1024];     // per-wave P scratch (reused per half)
  const int tid = threadIdx.x, wave = tid >> 6, lane = tid & 63;
  const int quad = lane >> 4, l16 = lane & 15;
  const int qb = blockIdx.x & 15;   // Sq/128
  const int bh = blockIdx.x >> 4;
  const int b = bh >> 4, h = bh & 15;
  const int q0 = qb * 128 + wave * 32;

  bf16x8 aq[2][4];
#pragma unroll
  for (int u = 0; u < 2; u++) {
    const unsigned short* qrow = Q + ((size_t)bh * S_ + q0 + u * 16 + l16) * HD;
#pragma unroll
    for (int t = 0; t < 4; t++) aq[u][t] = *(const bf16x8*)(qrow + t * 32 + quad * 8);
  }
  f32x4 o[2][8];
#pragma unroll
  for (int u = 0; u < 2; u++)
#pragma unroll
    for (int t = 0; t < 8; t++) o[u][t] = (f32x4){0.f, 0.f, 0.f, 0.f};
  float lsum[2][4] = {{0.f, 0.f, 0.f, 0.f}, {0.f, 0.f, 0.f, 0.f}};

  const unsigned short* kbase = Kt + (size_t)bh * S_ * HD;
  const unsigned short* vbase = Vt + (size_t)bh * HD * S_;
  unsigned short* lPw = lP + wave * 1024;
  const int mrow = quad * 4;
  const int xsl = (l16 >> 1) & 3;    // P-read swizzle (4 chunks per 32-key row)
  const int xsl7 = (l16 >> 1) & 7;   // V-read swizzle (8 chunks per 64-key row)

  // Stage one 64-key tile (K 16KB + V 16KB) into buffer BUF.
  // 2048 chunks of 16B over 256 threads = 8 calls -> 8 loads/thread.
#define STAGEKV(K0, BUF)                                                       \
  {                                                                            \
    const unsigned short* kb_ = kbase + (size_t)(K0) * HD;                     \
    const unsigned short* vb_ = vbase + (K0);                                  \
    _Pragma("unroll")                                                          \
    for (int call = 0; call < 4; ++call) {                                     \
      int c = call * 256 + tid;               /* chunk id [0,1024) */          \
      int key = c >> 4, sk = c & 15;          /* K: 64 keys x 16 dim-chunks */ \
      int dck = sk ^ (key & 15);                                               \
      STG(kb_ + (size_t)key * HD + dck * 8,                                    \
          lK + (BUF) * 8192 + (call * 256 + wave * 64) * 8);                   \
      int dv = c >> 3, sv = c & 7;            /* V: 128 dims x 8 key-chunks */ \
      int kc = sv ^ ((dv >> 1) & 7);                                           \
      STG(vb_ + (size_t)dv * S_ + kc * 8,                                      \
          lV + (BUF) * 8192 + (call * 256 + wave * 64) * 8);                   \
    }                                                                          \
  }

  STAGEKV(0, 0)

  for (int it = 0; it < S_ / 64; ++it) {
    // issue next tile's loads, then gate on the current tile (own loads only)
    if (it + 1 < S_ / 64) {
      STAGEKV((it + 1) * 64, (it + 1) & 1)
      asm volatile("s_waitcnt vmcnt(8)" ::: "memory");
    } else {
      asm volatile("s_waitcnt vmcnt(0)" ::: "memory");
    }
    __builtin_amdgcn_s_barrier();   // publish all waves' stages of tile `it`

    const unsigned short* lKc = lK + (it & 1) * 8192;
    const unsigned short* lVc = lV + (it & 1) * 8192;

#pragma unroll
    for (int h2 = 0; h2 < 2; ++h2) {          // two 32-key halves
      // S = Q*K^T  (two 16-key tiles x two 16-row q subtiles; K frags shared)
      f32x4 s0[2] = {(f32x4){0.f, 0.f, 0.f, 0.f}, (f32x4){0.f, 0.f, 0.f, 0.f}};
      f32x4 s1[2] = {(f32x4){0.f, 0.f, 0.f, 0.f}, (f32x4){0.f, 0.f, 0.f, 0.f}};
      {
        const unsigned short* krow0 = lKc + (h2 * 32 + l16) * HD;
        const unsigned short* krow1 = krow0 + 16 * HD;
        __builtin_amdgcn_s_setprio(1);
#pragma unroll
        for (int t = 0; t < 4; t++) {
          int dcq = t * 4 + quad;
          bf16x8 kf0 = *(const bf16x8*)(krow0 + (dcq ^ l16) * 8);
          bf16x8 kf1 = *(const bf16x8*)(krow1 + (dcq ^ l16) * 8);
#pragma unroll
          for (int u = 0; u < 2; u++) {
            s0[u] = __builtin_amdgcn_mfma_f32_16x16x32_bf16(aq[u][t], kf0, s0[u], 0, 0, 0);
            s1[u] = __builtin_amdgcn_mfma_f32_16x16x32_bf16(aq[u][t], kf1, s1[u], 0, 0, 0);
          }
        }
        __builtin_amdgcn_s_setprio(0);
      }
      // softmax numerator (no max subtraction: |s| <= 22.6)
#pragma unroll
      for (int u = 0; u < 2; u++) {
        unsigned short* lPu = lPw + u * 512;
#pragma unroll
        for (int r = 0; r < 4; r++) {
          int m = mrow + r;
          int sx = (m >> 1) & 3;
          float p0 = __expf(s0[u][r]);
          float p1 = __expf(s1[u][r]);
          lsum[u][r] += p0 + p1;
          int kc0 = l16 >> 3;
          lPu[m * 32 + ((kc0 ^ sx)) * 8 + (l16 & 7)] = f2bf(p0);
          lPu[m * 32 + (((kc0 + 2) ^ sx)) * 8 + (l16 & 7)] = f2bf(p1);
        }
      }
      // P: C-layout -> A-layout via LDS (in-wave ordered, no barrier needed)
      bf16x8 pf[2];
#pragma unroll
      for (int u = 0; u < 2; u++)
        pf[u] = *(const bf16x8*)(lPw + u * 512 + l16 * 32 + (quad ^ xsl) * 8);
      // O += P * V  (V frags shared across u)
      __builtin_amdgcn_s_setprio(1);
#pragma unroll
      for (int t = 0; t < 8; t++) {
        bf16x8 vf = *(const bf16x8*)(lVc + (t * 16 + l16) * 64 + ((h2 * 4 + quad) ^ xsl7) * 8);
#pragma unroll
        for (int u = 0; u < 2; u++)
          o[u][t] = __builtin_amdgcn_mfma_f32_16x16x32_bf16(pf[u], vf, o[u][t], 0, 0, 0);
      }
      __builtin_amdgcn_s_setprio(0);
    }

    __builtin_amdgcn_s_barrier();   // reads of buf (it&1) done before overwrite
  }
#undef STAGEKV

  // reduce row-sums across the 16 lanes of each quad
#pragma unroll
  for (int off = 1; off < 16; off <<= 1) {
#pragma unroll
    for (int u = 0; u < 2; u++)
#pragma unroll
      for (int r = 0; r < 4; r++) lsum[u][r] += __shfl_xor(lsum[u][r], off);
  }
  float inv[2][4];
#pragma unroll
  for (int u = 0; u < 2; u++)
#pragma unroll
    for (int r = 0; r < 4; r++) inv[u][r] = 1.0f / lsum[u][r];
#pragma unroll
  for (int u = 0; u < 2; u++)
#pragma unroll
    for (int t = 0; t < 8; t++)
#pragma unroll
      for (int r = 0; r < 4; r++) {
        size_t idx = ((size_t)b * S_ + q0 + u * 16 + mrow + r) * DM + h * HD + t * 16 + l16;
        Y[idx] = f2bf(o[u][t][r] * inv[u][r]);
      }
}

// ============================================================================
extern "C" void kernel_launch(void* const* d_in, const int* in_sizes, int n_in,
                              void* d_out, int out_size, void* d_ws, size_t ws_size,
                              hipStream_t stream) {
  const float* x    = (const float*)d_in[0];
  const float* ctx  = (const float*)d_in[1];
  const float* cosq = (const float*)d_in[2];
  const float* sinq = (const float*)d_in[3];
  const float* cosk = (const float*)d_in[4];
  const float* sink = (const float*)d_in[5];
  const float* Wq   = (const float*)d_in[6];
  const float* Wk   = (const float*)d_in[7];
  const float* Wv   = (const float*)d_in[8];
  const float* Wo   = (const float*)d_in[9];
  const float* qw   = (const float*)d_in[10];
  const float* kw   = (const float*)d_in[11];

  // ---- workspace layout with lifetime overlap (~118 MB) ----
  char* ws = (char*)d_ws;
  const size_t ACT2 = (size_t)M_ * DM * 2;   // 16.8 MB bf16 activation
  const size_t W2   = (size_t)DM * DM * 2;   // 8.4 MB bf16 weight
  unsigned short* xb  = (unsigned short*)(ws);                    // -> qn
  unsigned short* cb  = (unsigned short*)(ws + ACT2);             // -> vt
  unsigned short* Wqb = (unsigned short*)(ws + 2 * ACT2);         // \ kn
  unsigned short* Wkb = (unsigned short*)(ws + 2 * ACT2 + W2);    // /
  unsigned short* Wvb = (unsigned short*)(ws + 2 * ACT2 + 2 * W2);
  unsigned short* Wob = (unsigned short*)(ws + 2 * ACT2 + 3 * W2);
  unsigned short* Pq  = (unsigned short*)(ws + 2 * ACT2 + 4 * W2);  // -> yb
  unsigned short* Pk  = (unsigned short*)(ws + 3 * ACT2 + 4 * W2);
  unsigned short* Pv  = (unsigned short*)(ws + 4 * ACT2 + 4 * W2);
  unsigned short* qn = xb;          // after gemm_qkv consumed xb
  unsigned short* kn = Wqb;         // spans Wqb+Wkb, dead after gemm_qkv
  unsigned short* vt = cb;          // after gemm_qkv consumed cb
  unsigned short* yb = Pq;          // after normrope consumed Pq

  const float scale = 0.0883883476483184f;  // 1/sqrt(128)

  castbf<<<M_ * DM / 1024, 256, 0, stream>>>(x, xb, M_ * DM / 4);
  castbf<<<M_ * DM / 1024, 256, 0, stream>>>(ctx, cb, M_ * DM / 4);
  castbf<<<DM * DM / 1024, 256, 0, stream>>>(Wq, Wqb, DM * DM / 4);
  castbf<<<DM * DM / 1024, 256, 0, stream>>>(Wk, Wkb, DM * DM / 4);
  castbf<<<DM * DM / 1024, 256, 0, stream>>>(Wv, Wvb, DM * DM / 4);
  castbf<<<DM * DM / 1024, 256, 0, stream>>>(Wo, Wob, DM * DM / 4);

  dim3 gq(M_ / 128, DM / 256, 3);   // 32 x 8 x 3 = 768 blocks (2 per CU)
  gemm_qkv<<<gq, 256, 0, stream>>>(xb, cb, Wqb, Wkb, Wvb, Pq, Pk, Pv);

  normrope<<<M_ * H_ / 4, 256, 0, stream>>>(Pq, cosq, sinq, qw, qn, scale);
  normrope<<<M_ * H_ / 4, 256, 0, stream>>>(Pk, cosk, sink, kw, kn, 1.0f);
  vtrans<<<B_ * H_ * (S_ / 64), 256, 0, stream>>>(Pv, vt);

  flash<<<B_ * H_ * (S_ / 128), 256, 0, stream>>>(qn, kn, vt, yb);

  dim3 gg(M_ / 128, DM / 256);      // 32 x 8 = 256 blocks
  gemm_bt<<<gg, 256, 0, stream>>>(yb, Wob, (float*)d_out);

  (void)in_sizes; (void)n_in; (void)out_size; (void)ws_size;
}

// Round 5
// 455.801 us; speedup vs baseline: 1.0952x; 1.0036x over previous
//
#include <hip/hip_runtime.h>

// ============================================================================
// AdapterAttention on gfx950.
// R7: GEMM K-step phased (m201 shape). R6 analysis: wall 2786 cyc/K-step vs
//     1242 cyc MFMA demand (= MfmaUtil 40%); 1-phase counted-vmcnt leaves
//     read+gate+barrier exposed (regime gate: T5/T2 pay only inside the fine
//     phase interleave). Now per K-step(32): phase A {8 ds_read | stage H0 |
//     barrier | setprio 16 MFMA | barrier}, phase B {4 ds_read | stage H1 |
//     vmcnt(6) gate | barrier | setprio 16 MFMA | barrier} — 16 MFMA per
//     2 barriers, m201 ratio. Ring-3 spine, no drain until the tail.
//     flash (R6: dbuf + vmcnt(8), 256thr/128q) unchanged; geometry unchanged
//     (BM=128 BN=256 BK=32, wave-tile 128x64, 2 blocks/CU).
// ============================================================================

typedef __attribute__((ext_vector_type(8))) short bf16x8;
typedef __attribute__((ext_vector_type(4))) float f32x4;

#define AS1(p) ((__attribute__((address_space(1))) void*)(p))
#define AS3(p) ((__attribute__((address_space(3))) void*)(p))
#define STG(g, l) __builtin_amdgcn_global_load_lds(AS1(g), AS3(l), 16, 0, 0)

__device__ __forceinline__ unsigned short f2bf(float f) {
  unsigned int u = __float_as_uint(f);
  u += 0x7fffu + ((u >> 16) & 1u);   // RNE; inputs are finite
  return (unsigned short)(u >> 16);
}
__device__ __forceinline__ float bf2f(unsigned short u) {
  return __uint_as_float(((unsigned int)u) << 16);
}

constexpr int B_ = 2, S_ = 2048, DM = 2048, H_ = 16, HD = 128;
constexpr int M_ = B_ * S_;  // 4096 rows

// ---------------- fp32 -> bf16 cast (vec4) ----------------
__global__ __launch_bounds__(256) void castbf(const float* __restrict__ X,
                                              unsigned short* __restrict__ Y, int n4) {
  int i = blockIdx.x * 256 + threadIdx.x;
  if (i >= n4) return;
  float4 v = ((const float4*)X)[i];
  ushort4 u;
  u.x = f2bf(v.x); u.y = f2bf(v.y); u.z = f2bf(v.z); u.w = f2bf(v.w);
  ((ushort4*)Y)[i] = u;
}

// ---------------- phased high-density GEMM core: C = A * W^T ----------------
// BM=128, BN=256, BK=32. 256 threads = 4 waves (1M x 4N); wave-tile 128x64 =
// 8x4 frags = 32 MFMA per K-step per wave. LDS ring: 3 slots x 24 KB = 72 KB.
// Per K-step: 2 phases, each {ds_read subtile | stage 3 loads | [gate] |
// barrier | setprio(1) 16 MFMA setprio(0) | barrier}. Stage targets slot
// (t+2)%3 (never the slot being read). Gate vmcnt(6) once per K-step ensures
// tile t+1 landed while t+2's 6 loads stay in flight; drains only at tail.
template <int BF16OUT>
__device__ __forceinline__ void gemm_core(const unsigned short* __restrict__ A,
                                          const unsigned short* __restrict__ Bw,
                                          void* __restrict__ Cv,
                                          unsigned short* lds) {
  const int tid = threadIdx.x, wave = tid >> 6, lane = tid & 63;
  const int quad = lane >> 4, l16 = lane & 15;
  const int m0 = blockIdx.x * 128, n0 = blockIdx.y * 256;
  const int wn = wave * 64;
  constexpr int NT = DM / 32;     // 64 K-steps
  constexpr int SLOT = 12288;     // shorts per ring slot (24 KB)

  f32x4 acc[8][4];
#pragma unroll
  for (int f = 0; f < 8; f++)
#pragma unroll
    for (int g = 0; g < 4; g++) acc[f][g] = (f32x4){0.f, 0.f, 0.f, 0.f};

  // -- staging sources (per-lane, pre-swizzled). Chunk c: L=c>>3, phys=c&7,
  //    j = phys ^ (L&7); stored element = row (L + rowhalf*{64|128}),
  //    k-chunk j&3. LDS dest is linear: offset c*8 shorts.
  const unsigned short* srcA[2];
  const unsigned short* srcB[4];
#pragma unroll
  for (int i = 0; i < 2; i++) {
    int c = tid + i * 256, L = c >> 3, ph = c & 7, j = ph ^ (L & 7);
    srcA[i] = A + (size_t)(m0 + L + ((j >> 2) << 6)) * DM + (j & 3) * 8;
  }
#pragma unroll
  for (int i = 0; i < 4; i++) {
    int c = tid + i * 256, L = c >> 3, ph = c & 7, j = ph ^ (L & 7);
    srcB[i] = Bw + (size_t)(n0 + L + ((j >> 2) << 7)) * DM + (j & 3) * 8;
  }

  // per-tile staging split into two 3-load halves (phase A / phase B)
#define STAGE_H0(T, S)                                                         \
  { const int ko = (T) << 5; unsigned short* lb = lds + (S) * SLOT + wave * 512;\
    STG(srcA[0] + ko, lb);                                                     \
    STG(srcA[1] + ko, lb + 2048);                                              \
    STG(srcB[0] + ko, lb + 4096); }
#define STAGE_H1(T, S)                                                         \
  { const int ko = (T) << 5; unsigned short* lb = lds + (S) * SLOT + wave * 512;\
    STG(srcB[1] + ko, lb + 6144);                                              \
    STG(srcB[2] + ko, lb + 8192);                                              \
    STG(srcB[3] + ko, lb + 10240); }

  // -- read-side offsets (shorts). A frag f: row r=f*16+l16, line L=r&63,
  //    j = ((f>>2)<<2)|quad, phys = j^(l16&7). B frag g: row rb=wn+g*16+l16,
  //    line L=rb&127, j = ((wave>>1)<<2)|quad.
  const int x8 = l16 & 7;
  const int ab0 = l16 * 64 + ((quad ^ x8)) * 8;            // A frags 0..3
  const int ab1 = l16 * 64 + (((4 | quad) ^ x8)) * 8;      // A frags 4..7
  const int bb  = 4096 + (wn & 64) * 64 + l16 * 64 +
                  ((((wave >> 1) << 2) | quad) ^ x8) * 8;  // B frags (+g*1024)

  // -- prologue: stage tiles 0,1; gate tile 0 (tile 1's 6 stay in flight) --
  STAGE_H0(0, 0) STAGE_H1(0, 0)
  STAGE_H0(1, 1) STAGE_H1(1, 1)
  asm volatile("s_waitcnt vmcnt(6)" ::: "memory");
  __builtin_amdgcn_s_barrier();

  int st = 0, s2 = 2;
  for (int t = 0; t < NT; ++t) {
    const unsigned short* ls = lds + st * SLOT;

    // ---- phase A: A frags 0..3 + all B frags; stage half 0 of tile t+2 ----
    bf16x8 af0[4], bfv[4];
#pragma unroll
    for (int f = 0; f < 4; f++) af0[f] = *(const bf16x8*)(ls + f * 1024 + ab0);
#pragma unroll
    for (int g = 0; g < 4; g++) bfv[g] = *(const bf16x8*)(ls + g * 1024 + bb);
    if (t + 2 < NT) STAGE_H0(t + 2, s2)
    __builtin_amdgcn_s_barrier();
    __builtin_amdgcn_s_setprio(1);
#pragma unroll
    for (int f = 0; f < 4; f++)
#pragma unroll
      for (int g = 0; g < 4; g++)
        acc[f][g] = __builtin_amdgcn_mfma_f32_16x16x32_bf16(af0[f], bfv[g], acc[f][g], 0, 0, 0);
    __builtin_amdgcn_s_setprio(0);
    __builtin_amdgcn_s_barrier();

    // ---- phase B: A frags 4..7 (B reused); stage half 1; gate once/K-step --
    bf16x8 af1[4];
#pragma unroll
    for (int f = 0; f < 4; f++) af1[f] = *(const bf16x8*)(ls + f * 1024 + ab1);
    if (t + 2 < NT) STAGE_H1(t + 2, s2)
    // gate: tile t+1 fully landed; tile t+2's 6 loads stay in flight
    if (t < NT - 2)       asm volatile("s_waitcnt vmcnt(6)" ::: "memory");
    else if (t == NT - 2) asm volatile("s_waitcnt vmcnt(0)" ::: "memory");
    __builtin_amdgcn_s_barrier();
    __builtin_amdgcn_s_setprio(1);
#pragma unroll
    for (int f = 0; f < 4; f++)
#pragma unroll
      for (int g = 0; g < 4; g++)
        acc[f + 4][g] = __builtin_amdgcn_mfma_f32_16x16x32_bf16(af1[f], bfv[g], acc[f + 4][g], 0, 0, 0);
    __builtin_amdgcn_s_setprio(0);
    if (t < NT - 1) __builtin_amdgcn_s_barrier();

    st++; if (st == 3) st = 0;
    s2++; if (s2 == 3) s2 = 0;
  }
#undef STAGE_H0
#undef STAGE_H1

  // ---- epilogue: C write ----
#pragma unroll
  for (int f = 0; f < 8; f++)
#pragma unroll
    for (int g = 0; g < 4; g++) {
      const size_t row = (size_t)(m0 + f * 16 + quad * 4);
      const int col = n0 + wn + g * 16 + l16;
      if (BF16OUT) {
        unsigned short* cp = (unsigned short*)Cv + row * DM + col;
#pragma unroll
        for (int r = 0; r < 4; r++) cp[(size_t)r * DM] = f2bf(acc[f][g][r]);
      } else {
        float* cp = (float*)Cv + row * DM + col;
#pragma unroll
        for (int r = 0; r < 4; r++) cp[(size_t)r * DM] = acc[f][g][r];
      }
    }
}

// ---------------- batched QKV GEMM: P[z] = A[z] * W[z]^T, bf16 out ----------
__global__ __launch_bounds__(256, 2) void gemm_qkv(const unsigned short* __restrict__ xb,
                                                   const unsigned short* __restrict__ cb,
                                                   const unsigned short* __restrict__ Wq,
                                                   const unsigned short* __restrict__ Wk,
                                                   const unsigned short* __restrict__ Wv,
                                                   unsigned short* __restrict__ Pq,
                                                   unsigned short* __restrict__ Pk,
                                                   unsigned short* __restrict__ Pv) {
  __shared__ __align__(16) unsigned short lds[3 * 12288];  // 72 KiB
  const int z = blockIdx.z;
  const unsigned short* A  = (z == 0) ? xb : cb;
  const unsigned short* Bw = (z == 0) ? Wq : (z == 1) ? Wk : Wv;
  unsigned short* C        = (z == 0) ? Pq : (z == 1) ? Pk : Pv;
  gemm_core<1>(A, Bw, C, lds);
}

// ---------------- bf16 GEMM: C = A * W^T (fp32 out), for out-proj -----------
__global__ __launch_bounds__(256, 2) void gemm_bt(const unsigned short* __restrict__ A,
                                                  const unsigned short* __restrict__ Bw,
                                                  float* __restrict__ C) {
  __shared__ __align__(16) unsigned short lds[3 * 12288];  // 72 KiB
  gemm_core<0>(A, Bw, C, lds);
}

// ---------------- fused RMSNorm + RoPE, bf16 (B,S,H,hd) -> (B,H,S,hd) bf16 --
__global__ __launch_bounds__(256) void normrope(const unsigned short* __restrict__ X,
                                                const float* __restrict__ Cs,
                                                const float* __restrict__ Sn,
                                                const float* __restrict__ W,
                                                unsigned short* __restrict__ Out,
                                                float scale) {
  int gw = (blockIdx.x * 256 + threadIdx.x) >> 6;  // (b*S+s)*H + h
  int lane = threadIdx.x & 63;
  int h = gw & 15, bs = gw >> 4;          // bs = b*S + s
  int s = bs & (S_ - 1), b = bs >> 11;
  const unsigned short* xr = X + (size_t)gw * HD;
  float x0 = bf2f(xr[lane]), x1 = bf2f(xr[lane + 64]);
  float ss = x0 * x0 + x1 * x1;
#pragma unroll
  for (int off = 32; off > 0; off >>= 1) ss += __shfl_xor(ss, off);
  float rr = rsqrtf(ss * (1.0f / 128.0f) + 1e-6f);
  float n0 = x0 * rr * W[lane], n1 = x1 * rr * W[lane + 64];
  const float* cp = Cs + (size_t)bs * HD;
  const float* sp = Sn + (size_t)bs * HD;
  float o0 = (n0 * cp[lane] - n1 * sp[lane]) * scale;
  float o1 = (n1 * cp[lane + 64] + n0 * sp[lane + 64]) * scale;
  unsigned short* orow = Out + (((size_t)(b * H_ + h)) * S_ + s) * HD;
  orow[lane] = f2bf(o0);
  orow[lane + 64] = f2bf(o1);
}

// ---------------- V: bf16 (B,S,H,hd) -> (B*H, hd, Sk) bf16 (transposed) -----
__global__ __launch_bounds__(256) void vtrans(const unsigned short* __restrict__ Vf,
                                              unsigned short* __restrict__ Vt) {
  __shared__ unsigned short tile[128 * 72];  // [d][s], stride 72
  const int tid = threadIdx.x;
  const int sc = blockIdx.x & 31;
  const int bh = blockIdx.x >> 5;
  const int b = bh >> 4, h = bh & 15;
  const int s0 = sc * 64;
#pragma unroll
  for (int it = 0; it < 4; ++it) {
    int ci = it * 256 + tid;                  // 1024 chunks: 64 s x 16 dc
    int s = ci >> 4, dc = ci & 15;
    bf16x8 v = *(const bf16x8*)(Vf + ((size_t)(b * S_ + s0 + s)) * DM + h * HD + dc * 8);
    unsigned short* tp = tile + (dc * 8) * 72 + s;
#pragma unroll
    for (int e = 0; e < 8; e++) tp[e * 72] = (unsigned short)v[e];
  }
  __syncthreads();
#pragma unroll
  for (int it = 0; it < 4; ++it) {
    int cj = it * 256 + tid;                  // 1024 16B chunks: 128 d x 8 sc
    int d = cj >> 3, scx = cj & 7;
    bf16x8 vv = *(const bf16x8*)(tile + d * 72 + scx * 8);
    *(bf16x8*)(Vt + ((size_t)bh * HD + d) * S_ + s0 + scx * 8) = vv;
  }
}

// ---------------- flash attention v4 ----------------
// 256 threads (4 waves), 128 q-rows/block (32/wave), 64-key chunks.
// K/V double-buffered (2x16KB each); stage tile t+1 during compute of t;
// counted vmcnt(8) gates (8 loads/thread/tile in flight); raw s_barriers;
// no drain until the final iteration. Grid 512 = exactly 2 blocks/CU.
// Q (BH,Sq,128) bf16 scale-baked; K (BH,Sk,128); V (BH,128,Sk); Y (B,Sq,2048) bf16
__global__ __launch_bounds__(256, 2) void flash(const unsigned short* __restrict__ Q,
                                                const unsigned short* __restrict__ Kt,
                                                const unsigned short* __restrict__ Vt,
                                                unsigned short* __restrict__ Y) {
  __shared__ unsigned short lK[2 * 64 * HD];  // [buf][key][dim], chunk-swizzled
  __shared__ unsigned short lV[2 * HD * 64];  // [buf][dim][key], chunk-swizzled
  __shared__ unsigned short lP[4 * 1024];     // per-wave P scratch (reused per half)
  const int tid = threadIdx.x, wave = tid >> 6, lane = tid & 63;
  const int quad = lane >> 4, l16 = lane & 15;
  const int qb = blockIdx.x & 15;   // Sq/128
  const int bh = blockIdx.x >> 4;
  const int b = bh >> 4, h = bh & 15;
  const int q0 = qb * 128 + wave * 32;

  bf16x8 aq[2][4];
#pragma unroll
  for (int u = 0; u < 2; u++) {
    const unsigned short* qrow = Q + ((size_t)bh * S_ + q0 + u * 16 + l16) * HD;
#pragma unroll
    for (int t = 0; t < 4; t++) aq[u][t] = *(const bf16x8*)(qrow + t * 32 + quad * 8);
  }
  f32x4 o[2][8];
#pragma unroll
  for (int u = 0; u < 2; u++)
#pragma unroll
    for (int t = 0; t < 8; t++) o[u][t] = (f32x4){0.f, 0.f, 0.f, 0.f};
  float lsum[2][4] = {{0.f, 0.f, 0.f, 0.f}, {0.f, 0.f, 0.f, 0.f}};

  const unsigned short* kbase = Kt + (size_t)bh * S_ * HD;
  const unsigned short* vbase = Vt + (size_t)bh * HD * S_;
  unsigned short* lPw = lP + wave * 1024;
  const int mrow = quad * 4;
  const int xsl = (l16 >> 1) & 3;    // P-read swizzle (4 chunks per 32-key row)
  const int xsl7 = (l16 >> 1) & 7;   // V-read swizzle (8 chunks per 64-key row)

  // Stage one 64-key tile (K 16KB + V 16KB) into buffer BUF.
  // 2048 chunks of 16B over 256 threads = 8 calls -> 8 loads/thread.
#define STAGEKV(K0, BUF)                                                       \
  {                                                                            \
    const unsigned short* kb_ = kbase + (size_t)(K0) * HD;                     \
    const unsigned short* vb_ = vbase + (K0);                                  \
    _Pragma("unroll")                                                          \
    for (int call = 0; call < 4; ++call) {                                     \
      int c = call * 256 + tid;               /* chunk id [0,1024) */          \
      int key = c >> 4, sk = c & 15;          /* K: 64 keys x 16 dim-chunks */ \
      int dck = sk ^ (key & 15);                                               \
      STG(kb_ + (size_t)key * HD + dck * 8,                                    \
          lK + (BUF) * 8192 + (call * 256 + wave * 64) * 8);                   \
      int dv = c >> 3, sv = c & 7;            /* V: 128 dims x 8 key-chunks */ \
      int kc = sv ^ ((dv >> 1) & 7);                                           \
      STG(vb_ + (size_t)dv * S_ + kc * 8,                                      \
          lV + (BUF) * 8192 + (call * 256 + wave * 64) * 8);                   \
    }                                                                          \
  }

  STAGEKV(0, 0)

  for (int it = 0; it < S_ / 64; ++it) {
    // issue next tile's loads, then gate on the current tile (own loads only)
    if (it + 1 < S_ / 64) {
      STAGEKV((it + 1) * 64, (it + 1) & 1)
      asm volatile("s_waitcnt vmcnt(8)" ::: "memory");
    } else {
      asm volatile("s_waitcnt vmcnt(0)" ::: "memory");
    }
    __builtin_amdgcn_s_barrier();   // publish all waves' stages of tile `it`

    const unsigned short* lKc = lK + (it & 1) * 8192;
    const unsigned short* lVc = lV + (it & 1) * 8192;

#pragma unroll
    for (int h2 = 0; h2 < 2; ++h2) {          // two 32-key halves
      // S = Q*K^T  (two 16-key tiles x two 16-row q subtiles; K frags shared)
      f32x4 s0[2] = {(f32x4){0.f, 0.f, 0.f, 0.f}, (f32x4){0.f, 0.f, 0.f, 0.f}};
      f32x4 s1[2] = {(f32x4){0.f, 0.f, 0.f, 0.f}, (f32x4){0.f, 0.f, 0.f, 0.f}};
      {
        const unsigned short* krow0 = lKc + (h2 * 32 + l16) * HD;
        const unsigned short* krow1 = krow0 + 16 * HD;
        __builtin_amdgcn_s_setprio(1);
#pragma unroll
        for (int t = 0; t < 4; t++) {
          int dcq = t * 4 + quad;
          bf16x8 kf0 = *(const bf16x8*)(krow0 + (dcq ^ l16) * 8);
          bf16x8 kf1 = *(const bf16x8*)(krow1 + (dcq ^ l16) * 8);
#pragma unroll
          for (int u = 0; u < 2; u++) {
            s0[u] = __builtin_amdgcn_mfma_f32_16x16x32_bf16(aq[u][t], kf0, s0[u], 0, 0, 0);
            s1[u] = __builtin_amdgcn_mfma_f32_16x16x32_bf16(aq[u][t], kf1, s1[u], 0, 0, 0);
          }
        }
        __builtin_amdgcn_s_setprio(0);
      }
      // softmax numerator (no max subtraction: |s| <= 22.6)
#pragma unroll
      for (int u = 0; u < 2; u++) {
        unsigned short* lPu = lPw + u * 512;
#pragma unroll
        for (int r = 0; r < 4; r++) {
          int m = mrow + r;
          int sx = (m >> 1) & 3;
          float p0 = __expf(s0[u][r]);
          float p1 = __expf(s1[u][r]);
          lsum[u][r] += p0 + p1;
          int kc0 = l16 >> 3;
          lPu[m * 32 + ((kc0 ^ sx)) * 8 + (l16 & 7)] = f2bf(p0);
          lPu[m * 32 + (((kc0 + 2) ^ sx)) * 8 + (l16 & 7)] = f2bf(p1);
        }
      }
      // P: C-layout -> A-layout via LDS (in-wave ordered, no barrier needed)
      bf16x8 pf[2];
#pragma unroll
      for (int u = 0; u < 2; u++)
        pf[u] = *(const bf16x8*)(lPw + u * 512 + l16 * 32 + (quad ^ xsl) * 8);
      // O += P * V  (V frags shared across u)
      __builtin_amdgcn_s_setprio(1);
#pragma unroll
      for (int t = 0; t < 8; t++) {
        bf16x8 vf = *(const bf16x8*)(lVc + (t * 16 + l16) * 64 + ((h2 * 4 + quad) ^ xsl7) * 8);
#pragma unroll
        for (int u = 0; u < 2; u++)
          o[u][t] = __builtin_amdgcn_mfma_f32_16x16x32_bf16(pf[u], vf, o[u][t], 0, 0, 0);
      }
      __builtin_amdgcn_s_setprio(0);
    }

    __builtin_amdgcn_s_barrier();   // reads of buf (it&1) done before overwrite
  }
#undef STAGEKV

  // reduce row-sums across the 16 lanes of each quad
#pragma unroll
  for (int off = 1; off < 16; off <<= 1) {
#pragma unroll
    for (int u = 0; u < 2; u++)
#pragma unroll
      for (int r = 0; r < 4; r++) lsum[u][r] += __shfl_xor(lsum[u][r], off);
  }
  float inv[2][4];
#pragma unroll
  for (int u = 0; u < 2; u++)
#pragma unroll
    for (int r = 0; r < 4; r++) inv[u][r] = 1.0f / lsum[u][r];
#pragma unroll
  for (int u = 0; u < 2; u++)
#pragma unroll
    for (int t = 0; t < 8; t++)
#pragma unroll
      for (int r = 0; r < 4; r++) {
        size_t idx = ((size_t)b * S_ + q0 + u * 16 + mrow + r) * DM + h * HD + t * 16 + l16;
        Y[idx] = f2bf(o[u][t][r] * inv[u][r]);
      }
}

// ============================================================================
extern "C" void kernel_launch(void* const* d_in, const int* in_sizes, int n_in,
                              void* d_out, int out_size, void* d_ws, size_t ws_size,
                              hipStream_t stream) {
  const float* x    = (const float*)d_in[0];
  const float* ctx  = (const float*)d_in[1];
  const float* cosq = (const float*)d_in[2];
  const float* sinq = (const float*)d_in[3];
  const float* cosk = (const float*)d_in[4];
  const float* sink = (const float*)d_in[5];
  const float* Wq   = (const float*)d_in[6];
  const float* Wk   = (const float*)d_in[7];
  const float* Wv   = (const float*)d_in[8];
  const float* Wo   = (const float*)d_in[9];
  const float* qw   = (const float*)d_in[10];
  const float* kw   = (const float*)d_in[11];

  // ---- workspace layout with lifetime overlap (~118 MB) ----
  char* ws = (char*)d_ws;
  const size_t ACT2 = (size_t)M_ * DM * 2;   // 16.8 MB bf16 activation
  const size_t W2   = (size_t)DM * DM * 2;   // 8.4 MB bf16 weight
  unsigned short* xb  = (unsigned short*)(ws);                    // -> qn
  unsigned short* cb  = (unsigned short*)(ws + ACT2);             // -> vt
  unsigned short* Wqb = (unsigned short*)(ws + 2 * ACT2);         // \ kn
  unsigned short* Wkb = (unsigned short*)(ws + 2 * ACT2 + W2);    // /
  unsigned short* Wvb = (unsigned short*)(ws + 2 * ACT2 + 2 * W2);
  unsigned short* Wob = (unsigned short*)(ws + 2 * ACT2 + 3 * W2);
  unsigned short* Pq  = (unsigned short*)(ws + 2 * ACT2 + 4 * W2);  // -> yb
  unsigned short* Pk  = (unsigned short*)(ws + 3 * ACT2 + 4 * W2);
  unsigned short* Pv  = (unsigned short*)(ws + 4 * ACT2 + 4 * W2);
  unsigned short* qn = xb;          // after gemm_qkv consumed xb
  unsigned short* kn = Wqb;         // spans Wqb+Wkb, dead after gemm_qkv
  unsigned short* vt = cb;          // after gemm_qkv consumed cb
  unsigned short* yb = Pq;          // after normrope consumed Pq

  const float scale = 0.0883883476483184f;  // 1/sqrt(128)

  castbf<<<M_ * DM / 1024, 256, 0, stream>>>(x, xb, M_ * DM / 4);
  castbf<<<M_ * DM / 1024, 256, 0, stream>>>(ctx, cb, M_ * DM / 4);
  castbf<<<DM * DM / 1024, 256, 0, stream>>>(Wq, Wqb, DM * DM / 4);
  castbf<<<DM * DM / 1024, 256, 0, stream>>>(Wk, Wkb, DM * DM / 4);
  castbf<<<DM * DM / 1024, 256, 0, stream>>>(Wv, Wvb, DM * DM / 4);
  castbf<<<DM * DM / 1024, 256, 0, stream>>>(Wo, Wob, DM * DM / 4);

  dim3 gq(M_ / 128, DM / 256, 3);   // 32 x 8 x 3 = 768 blocks (2 per CU)
  gemm_qkv<<<gq, 256, 0, stream>>>(xb, cb, Wqb, Wkb, Wvb, Pq, Pk, Pv);

  normrope<<<M_ * H_ / 4, 256, 0, stream>>>(Pq, cosq, sinq, qw, qn, scale);
  normrope<<<M_ * H_ / 4, 256, 0, stream>>>(Pk, cosk, sink, kw, kn, 1.0f);
  vtrans<<<B_ * H_ * (S_ / 64), 256, 0, stream>>>(Pv, vt);

  flash<<<B_ * H_ * (S_ / 128), 256, 0, stream>>>(qn, kn, vt, yb);

  dim3 gg(M_ / 128, DM / 256);      // 32 x 8 = 256 blocks
  gemm_bt<<<gg, 256, 0, stream>>>(yb, Wob, (float*)d_out);

  (void)in_sizes; (void)n_in; (void)out_size; (void)ws_size;
}